// Round 12
// baseline (634.834 us; speedup 1.0000x reference)
//
#include <hip/hip_runtime.h>

typedef _Float16 half_t;
typedef _Float16 half8 __attribute__((ext_vector_type(8)));
typedef float floatx4 __attribute__((ext_vector_type(4)));

#define MFMA(a,b,c) __builtin_amdgcn_mfma_f32_16x16x32_f16(a,b,c,0,0,0)

#define NB 16
#define NLEN 1024
#define DD 128
#define BN (NB*NLEN)                       // 16384 rows per branch
#define BND ((size_t)NB*NLEN*DD)
#define EMP 1044                           // emS row stride

// ---------------- weight casts: gW->Wf16, gA+gA^T->ST16, Ew->EwF
__global__ __launch_bounds__(256)
void k_cast(const float* __restrict__ gW, const float* __restrict__ gA,
            const float* __restrict__ Ew,
            half_t* __restrict__ Wf, half_t* __restrict__ STf, half_t* __restrict__ EwF) {
    int i = blockIdx.x * 256 + threadIdx.x;
    if (i < 65536) {
        Wf[i] = (half_t)gW[i];
        int base = i & ~16383;
        int lrem = i & 16383;
        int d = lrem >> 7, e = lrem & 127;
        STf[base + (e << 7) + d] = (half_t)(gA[i] + gA[base + (e << 7) + d]);
    } else {
        int j = i - 65536;
        EwF[j] = (half_t)Ew[j];
    }
}

// ---------------- embed as MFMA GEMM: h16 = f16(x) @ EwF^T
__global__ __launch_bounds__(256)
void k_emb(const float* __restrict__ x, const half_t* __restrict__ EwF,
           half_t* __restrict__ h16) {
    __shared__ half_t htile[32 * 136];
    __shared__ half_t otile[32 * 136];
    int g = blockIdx.x * 32;
    int t = threadIdx.x;
    int w = t >> 6, l = t & 63, q = l >> 4, l15 = l & 15;
#pragma unroll
    for (int v = 0; v < 2; v++) {
        int idx = v * 256 + t; int r = idx >> 4, c8 = (idx & 15) * 8;
        const float* xp = &x[(size_t)(g + r) * DD + c8];
        float4 f0 = *(const float4*)xp;
        float4 f1 = *(const float4*)(xp + 4);
        half8 va;
        va[0] = (half_t)f0.x; va[1] = (half_t)f0.y; va[2] = (half_t)f0.z; va[3] = (half_t)f0.w;
        va[4] = (half_t)f1.x; va[5] = (half_t)f1.y; va[6] = (half_t)f1.z; va[7] = (half_t)f1.w;
        *(half8*)&htile[r * 136 + c8] = va;
    }
    __syncthreads();
    int rowh = (w & 1) * 16;
    int c0 = (w >> 1) * 4;
    half8 a1[4];
#pragma unroll
    for (int kc = 0; kc < 4; kc++) a1[kc] = *(const half8*)&htile[(rowh + l15) * 136 + kc * 32 + q * 8];
#pragma unroll
    for (int cc = 0; cc < 4; cc++) {
        int col = (c0 + cc) * 16 + l15;
        floatx4 a = {0.f, 0.f, 0.f, 0.f};
#pragma unroll
        for (int kc = 0; kc < 4; kc++) {
            half8 bf = *(const half8*)&EwF[((size_t)col << 7) + kc * 32 + q * 8];
            a = MFMA(a1[kc], bf, a);
        }
#pragma unroll
        for (int r = 0; r < 4; r++)
            otile[(rowh + q * 4 + r) * 136 + col] = (half_t)a[r];
    }
    __syncthreads();
#pragma unroll
    for (int v = 0; v < 2; v++) {
        int idx = v * 256 + t; int r = idx >> 4, c8 = (idx & 15) * 8;
        *(half8*)&h16[((size_t)(g + r) << 7) + c8] = *(const half8*)&otile[r * 136 + c8];
    }
}

// ---------------- adjacency bitmask build, coalesced via LDS bounce
__global__ __launch_bounds__(256)
void k_mask(const float* __restrict__ adj1, const float* __restrict__ adj2,
            unsigned short* __restrict__ mask16) {
    __shared__ float ls[4][1024];              // 16 KiB
    int tid = threadIdx.x;
    int bid = blockIdx.x;
    int w = tid >> 6, l = tid & 63;
    int R = bid * 4 + w;
    int br = R >> 14, nb = R & 16383;
    const float* arow = (br ? adj2 : adj1) + (size_t)nb * 1024;
#pragma unroll
    for (int c = 0; c < 4; c++)
        *(float4*)&ls[w][c * 256 + l * 4] = *(const float4*)&arow[c * 256 + l * 4];
    __syncthreads();
    unsigned m = 0u;
#pragma unroll
    for (int c = 0; c < 4; c++) {
        float4 v = *(const float4*)&ls[w][l * 16 + c * 4];
        m |= (v.x > 0.f ? 1u : 0u) << (c * 4);
        m |= (v.y > 0.f ? 1u : 0u) << (c * 4 + 1);
        m |= (v.z > 0.f ? 1u : 0u) << (c * 4 + 2);
        m |= (v.w > 0.f ? 1u : 0u) << (c * 4 + 3);
    }
    mask16[(size_t)R * 64 + l] = (unsigned short)m;
}

// ---------------- proj (MFMA): in = pa - pb (f16); hbr = in@W^T + b ; hS = hbr@S
__global__ __launch_bounds__(256)
void k_proj(const half_t* __restrict__ pa, const half_t* __restrict__ pb,
            const half_t* __restrict__ Wf, const float* __restrict__ bias,
            const half_t* __restrict__ STf,
            half_t* __restrict__ hbr16, half_t* __restrict__ hbrT,
            half_t* __restrict__ hbrF, half_t* __restrict__ hSF) {
    __shared__ half_t htile[32 * 136];
    __shared__ half_t hbtile[32 * 136];
    int g = blockIdx.x * 32;
    int t = threadIdx.x;
    int w = t >> 6, l = t & 63, q = l >> 4, l15 = l & 15;
#pragma unroll
    for (int v = 0; v < 2; v++) {
        int idx = v * 256 + t; int r = idx >> 4, c8 = (idx & 15) * 8;
        half8 va = *(const half8*)&pa[((size_t)(g + r) << 7) + c8];
        if (pb) {
            half8 vb = *(const half8*)&pb[((size_t)(g + r) << 7) + c8];
            va = va - vb;
        }
        *(half8*)&htile[r * 136 + c8] = va;
    }
    __syncthreads();
    int rowh = (w & 1) * 16;
    int c0 = (w >> 1) * 4;
    half8 a1[4];
#pragma unroll
    for (int kc = 0; kc < 4; kc++) a1[kc] = *(const half8*)&htile[(rowh + l15) * 136 + kc * 32 + q * 8];
    floatx4 acc[4];
#pragma unroll
    for (int cc = 0; cc < 4; cc++) {
        int col = (c0 + cc) * 16 + l15;
        floatx4 a = {0.f, 0.f, 0.f, 0.f};
#pragma unroll
        for (int kc = 0; kc < 4; kc++) {
            half8 bf = *(const half8*)&Wf[((size_t)col << 7) + kc * 32 + q * 8];
            a = MFMA(a1[kc], bf, a);
        }
        float bv = bias[col];
        a.x += bv; a.y += bv; a.z += bv; a.w += bv;
        acc[cc] = a;
    }
#pragma unroll
    for (int cc = 0; cc < 4; cc++) {
        int col = (c0 + cc) * 16 + l15;
#pragma unroll
        for (int r = 0; r < 4; r++)
            hbtile[(rowh + q * 4 + r) * 136 + col] = (half_t)acc[cc][r];
    }
    __syncthreads();
    half8 a2[4];
#pragma unroll
    for (int kc = 0; kc < 4; kc++) a2[kc] = *(const half8*)&hbtile[(rowh + l15) * 136 + kc * 32 + q * 8];
#pragma unroll
    for (int cc = 0; cc < 4; cc++) {
        int col = (c0 + cc) * 16 + l15;
        floatx4 a = {0.f, 0.f, 0.f, 0.f};
#pragma unroll
        for (int kc = 0; kc < 4; kc++) {
            half8 bf = *(const half8*)&STf[((size_t)col << 7) + kc * 32 + q * 8];
            a = MFMA(a2[kc], bf, a);
        }
        acc[cc] = a;
    }
    __syncthreads();
#pragma unroll
    for (int cc = 0; cc < 4; cc++) {
        int col = (c0 + cc) * 16 + l15;
#pragma unroll
        for (int r = 0; r < 4; r++) htile[(rowh + q * 4 + r) * 136 + col] = (half_t)acc[cc][r];
    }
    __syncthreads();
#pragma unroll
    for (int v = 0; v < 2; v++) {
        int idx = v * 256 + t; int r = idx >> 4, c8 = (idx & 15) * 8;
        *(half8*)&hbr16[((size_t)(g + r) << 7) + c8] = *(const half8*)&hbtile[r * 136 + c8];
    }
    // transposed hbr: hbrT[b][d][i]
    {
        int b_ = g >> 10, gi = g & 1023;
        int d = t >> 1, hh = t & 1;
        half8 r0, r1;
#pragma unroll
        for (int e = 0; e < 8; e++) {
            r0[e] = hbtile[(hh * 16 + e) * 136 + d];
            r1[e] = hbtile[(hh * 16 + 8 + e) * 136 + d];
        }
        half_t* op = hbrT + ((size_t)b_ * 128 + d) * 1024 + gi + hh * 16;
        *(half8*)op = r0;
        *(half8*)(op + 8) = r1;
    }
#pragma unroll
    for (int v = 0; v < 2; v++) {
        int fi = v * 256 + t;
        int g2 = fi >> 8, kc = (fi >> 6) & 3, li = fi & 63;
        int src = (g2 * 16 + (li & 15)) * 136 + kc * 32 + (li >> 4) * 8;
        size_t dst = (((size_t)(blockIdx.x * 2 + g2) * 4 + kc) << 10) + li * 8;
        *(half8*)&hbrF[dst] = *(const half8*)&hbtile[src];
        *(half8*)&hSF[dst]  = *(const half8*)&htile[src];
    }
}

// ---------------- E: em strip (MFMA) -> FRAGMENT-ORDER DmF (mask?exp:0),
// rowsums via shfl16/32, rsr, and B-fragment-order hbrsF (= rsr-scaled hbr).
// DmF slot ((br*16+b)*64+s)*32+jt : lane l=(q,l15) elem e = D[s*16+l15][jt*32+q*8+e]
// zF  slot (c*256+jt*8+nf)        : lane l=(q,l15) elem e = z[jt*32+q*8+e][nf*16+l15]
__global__ __launch_bounds__(256)
void k_E(const half_t* __restrict__ hSF, const half_t* __restrict__ hbrF,
         const unsigned short* __restrict__ mask16, const half_t* __restrict__ hbrT,
         half_t* __restrict__ DmF, float* __restrict__ rsr, half_t* __restrict__ hbrsF) {
    int hw = blockIdx.y * 64 + blockIdx.x;
    int wk = (hw & 7) * 128 + (hw >> 3);
    int b = wk >> 6, s = wk & 63;              // 64 strips of 16 rows per batch
    int t = threadIdx.x, w = t >> 6, l = t & 63, q = l >> 4, l15 = l & 15;
    __shared__ half_t emS[16 * EMP];
    __shared__ float rsP[4][16];
    __shared__ int   cnP[4][16];
    __shared__ float rsS[2][16];
    size_t Gb = (size_t)b * 64;
    half8 A[4];
#pragma unroll
    for (int kc = 0; kc < 4; kc++)
        A[kc] = *(const half8*)&hSF[(((Gb + s) * 4 + kc) << 10) + l * 8];
#pragma unroll 4
    for (int cg = 0; cg < 16; cg++) {
        int c0 = w * 256 + cg * 16;
        floatx4 a = {0.f, 0.f, 0.f, 0.f};
#pragma unroll
        for (int kc = 0; kc < 4; kc++) {
            half8 bf = *(const half8*)&hbrF[(((Gb + w * 16 + cg) * 4 + kc) << 10) + l * 8];
            a = MFMA(A[kc], bf, a);
        }
#pragma unroll
        for (int r = 0; r < 4; r++)
            emS[(q * 4 + r) * EMP + c0 + l15] = (half_t)a[r];
    }
    __syncthreads();
    const float CN = 0.000335462627903f;       // exp(-8)
    // frag phase: wave w -> (br = w&1, jt half = w>>1)
    {
        int br = w & 1, jbase = (w >> 1) * 16;
        size_t Rrow = ((size_t)br << 14) + (size_t)b * 1024 + s * 16 + l15;
        size_t slotbase = (((size_t)(br * 16 + b) * 64 + s) << 5) << 9;   // *32*512
        float rsl = 0.f;
        int cnl = 0;
        for (int jj = 0; jj < 16; jj++) {
            int jt = jbase + jj;
            half8 e = *(const half8*)&emS[l15 * EMP + jt * 32 + q * 8];
            unsigned mw = (unsigned)mask16[Rrow * 64 + jt * 2 + (q >> 1)];
            unsigned bits = (mw >> ((q & 1) * 8)) & 0xFFu;
            half8 o;
#pragma unroll
            for (int d = 0; d < 8; d++) {
                float v = ((bits >> d) & 1u) ? __expf((float)e[d] - 8.f) : 0.f;
                o[d] = (half_t)v;
                rsl += v;
            }
            cnl += __popc(bits);
            *(half8*)&DmF[slotbase + (size_t)jt * 512 + l * 8] = o;
        }
        rsl += __shfl_xor(rsl, 16); rsl += __shfl_xor(rsl, 32);
        cnl += __shfl_xor(cnl, 16); cnl += __shfl_xor(cnl, 32);
        if (l < 16) { rsP[w][l] = rsl; cnP[w][l] = cnl; }
    }
    __syncthreads();
    if (t < 32) {
        int brx = t >> 4, row = t & 15;
        float rs = rsP[brx][row] + rsP[brx + 2][row];
        int cn = cnP[brx][row] + cnP[brx + 2][row];
        float rv = 1.f / (rs + (1024.f - (float)cn) * CN);
        rsr[((size_t)brx << 14) + (size_t)b * 1024 + s * 16 + row] = rv;
        rsS[brx][row] = rv;
    }
    __syncthreads();
    // hbrsF: B-frag-order rsr-scaled hbr for this 16-j strip
    {
        int d = t >> 1, brx = t & 1;
        int nf = d >> 4, dd = d & 15, qo = (s & 1) * 2;
        const half_t* hp = hbrT + ((size_t)b * 128 + d) * 1024 + s * 16;
        half8 a0 = *(const half8*)hp, a1 = *(const half8*)(hp + 8);
        half8 r0, r1;
#pragma unroll
        for (int e = 0; e < 8; e++) {
            r0[e] = (half_t)((float)a0[e] * rsS[brx][e]);
            r1[e] = (half_t)((float)a1[e] * rsS[brx][8 + e]);
        }
        size_t slot = (((size_t)((brx << 4) + b) * 256 + (s >> 1) * 8 + nf)) << 9;
        *(half8*)&hbrsF[slot + (qo * 16 + dd) * 8] = r0;
        *(half8*)&hbrsF[slot + ((qo + 1) * 16 + dd) * 8] = r1;
    }
}

// ---------------- az GEMM v2: ZERO-barrier K-loop, fragment-direct operands.
// grid 512 = 32 slices x 16 tiles of 64 i (slice = bid&31 -> one XCD).
// 8 waves: (wi = strip 0..3, dh = d-half). Per jt: A-frag (contiguous 1KB from
// DmF, L3) + 4 B-frags (zF, L1/L2) -> 4 MFMA. 2-deep register prefetch.
// LDS only for 17KB epilogue tile. Epilogue math identical to prior rounds.
__global__ __launch_bounds__(512)
void k_azd(const half_t* __restrict__ DmF, const float* __restrict__ rsr,
           const half_t* __restrict__ zF, const half_t* __restrict__ hbr16,
           const float* __restrict__ gw, const float* __restrict__ gb_,
           float* __restrict__ cfb, half_t* __restrict__ outR, half_t* __restrict__ outF,
           int mode) {
    __shared__ half_t az[64][136];
    int t = threadIdx.x, w = t >> 6, l = t & 63, q = l >> 4, l15 = l & 15;
    int wi = w & 3, dh = w >> 2;
    int bid = blockIdx.x;
    int slice = bid & 31, tile = bid >> 5;
    int br = slice & 1, b = slice >> 1;
    int c = (br << 4) + b;
    int i0 = tile * 64;
    const half_t* Ap = DmF + (size_t)(c * 64 + tile * 4 + wi) * 16384 + l * 8;
    const half_t* Bp = zF + ((size_t)c * 256 + dh * 4) * 512 + l * 8;
    floatx4 acc[4] = {};
    half8 aC = *(const half8*)Ap;
    half8 bC0 = *(const half8*)(Bp);
    half8 bC1 = *(const half8*)(Bp + 512);
    half8 bC2 = *(const half8*)(Bp + 1024);
    half8 bC3 = *(const half8*)(Bp + 1536);
    for (int jt = 0; jt < 32; jt++) {
        half8 aN = aC, bN0 = bC0, bN1 = bC1, bN2 = bC2, bN3 = bC3;
        if (jt < 31) {
            const half_t* An = Ap + (size_t)(jt + 1) * 512;
            const half_t* Bn = Bp + (size_t)(jt + 1) * 4096;
            aN  = *(const half8*)An;
            bN0 = *(const half8*)(Bn);
            bN1 = *(const half8*)(Bn + 512);
            bN2 = *(const half8*)(Bn + 1024);
            bN3 = *(const half8*)(Bn + 1536);
        }
        acc[0] = MFMA(aC, bC0, acc[0]);
        acc[1] = MFMA(aC, bC1, acc[1]);
        acc[2] = MFMA(aC, bC2, acc[2]);
        acc[3] = MFMA(aC, bC3, acc[3]);
        aC = aN; bC0 = bN0; bC1 = bN1; bC2 = bN2; bC3 = bN3;
    }
#pragma unroll
    for (int nf = 0; nf < 4; nf++)
#pragma unroll
        for (int r = 0; r < 4; r++)
            az[wi * 16 + q * 4 + r][dh * 64 + nf * 16 + l15] = (half_t)acc[nf][r];
    __syncthreads();
#pragma unroll
    for (int it = 0; it < 2; it++) {
        int iloc = it * 32 + (t >> 4);         // 32 rows/pass, 16 lanes per row
        int i = i0 + iloc;
        int nb = b * 1024 + i;
        int R = c * 1024 + i;
        half8 az8 = *(const half8*)&az[iloc][l15 * 8];
        half8 hv8 = *(const half8*)&hbr16[((size_t)nb << 7) + l15 * 8];
        float av[8], hv[8];
#pragma unroll
        for (int d = 0; d < 8; d++) {
            av[d] = fmaxf((float)az8[d], 0.f);
            hv[d] = (float)hv8[d];
        }
        float cf;
        if (mode >= 3) {
            const float* g1 = gw + l15 * 8;
            const float* g2 = gw + 128 + l15 * 8;
            float dp = 0.f;
#pragma unroll
            for (int d = 0; d < 8; d++) dp += hv[d] * g1[d] + av[d] * g2[d];
            dp += __shfl_xor(dp, 1); dp += __shfl_xor(dp, 2);
            dp += __shfl_xor(dp, 4); dp += __shfl_xor(dp, 8);
            cf = 1.f / (1.f + __expf(-(dp + gb_[0])));
            if (l15 == 0) cfb[R] = cf;
        } else {
            cf = cfb[R];
        }
        if (mode == 2 || mode == 4) {
            half8 o;
#pragma unroll
            for (int d = 0; d < 8; d++) o[d] = (half_t)(cf * hv[d] + (1.f - cf) * av[d]);
            *(half8*)&outR[(size_t)R * DD + l15 * 8] = o;
        } else {
            float sc = rsr[R];
#pragma unroll
            for (int d = 0; d < 8; d++)
                az[iloc][l15 * 8 + d] = (half_t)(sc * (cf * hv[d] + (1.f - cf) * av[d]));
        }
    }
    if (mode == 1 || mode == 3) {
        __syncthreads();
        int d = t & 127, g4 = t >> 7;          // 4 chunks of 16 j
        int q0 = (g4 & 1) * 2;
        size_t slot = ((size_t)c * 256 + ((i0 >> 5) + (g4 >> 1)) * 8 + (d >> 4)) << 9;
        half8 r0, r1;
#pragma unroll
        for (int e = 0; e < 8; e++) {
            r0[e] = az[g4 * 16 + e][d];
            r1[e] = az[g4 * 16 + 8 + e][d];
        }
        *(half8*)&outF[slot + (q0 * 16 + (d & 15)) * 8] = r0;
        *(half8*)&outF[slot + ((q0 + 1) * 16 + (d & 15)) * 8] = r1;
    }
}

// ---------------- partial masked pool of (z2 - z1), f16 inputs
__global__ __launch_bounds__(256)
void k_pool(const half_t* __restrict__ z2, const half_t* __restrict__ z1,
            const float* __restrict__ valid, float* __restrict__ part) {
    int b = blockIdx.y, s = blockIdx.x;
    int t = threadIdx.x, d = t & 127, hf = t >> 7;
    __shared__ float red[128];
    float acc = 0.f;
    int nbase = s * 128 + hf * 64;
    for (int n = nbase; n < nbase + 64; n++) {
        size_t gi = ((size_t)(b * 1024 + n) << 7) + d;
        acc += ((float)z2[gi] - (float)z1[gi]) * valid[b * 1024 + n];
    }
    if (hf) red[d] = acc;
    __syncthreads();
    if (!hf) part[(b * 8 + s) * 128 + d] = acc + red[d];
}

// ---------------- final reduce + MLP head
__global__ __launch_bounds__(128)
void k_mlp(const float* __restrict__ part, const float* __restrict__ valid,
           const float* __restrict__ w0, const float* __restrict__ b0,
           const float* __restrict__ w1, const float* __restrict__ b1,
           const float* __restrict__ w2, const float* __restrict__ b2,
           const float* __restrict__ w3, const float* __restrict__ b3,
           float* __restrict__ out) {
    int b = blockIdx.x, t = threadIdx.x;
    __shared__ float y0[DD], y1[DD];
    __shared__ float sred[2];
    float vs = 0.f;
    for (int n = t; n < NLEN; n += 128) vs += valid[b * NLEN + n];
    for (int off = 32; off; off >>= 1) vs += __shfl_down(vs, off);
    if ((t & 63) == 0) sred[t >> 6] = vs;
    __syncthreads();
    float vsum = sred[0] + sred[1];
    float acc = 0.f;
#pragma unroll
    for (int s = 0; s < 8; s++) acc += part[(b * 8 + s) * 128 + t];
    y0[t] = acc / vsum;
    __syncthreads();
    float a = b0[t];
    for (int k = 0; k < DD; k++) a += y0[k] * w0[t * DD + k];
    y1[t] = fmaxf(a, 0.f);
    __syncthreads();
    a = b1[t];
    for (int k = 0; k < DD; k++) a += y1[k] * w1[t * DD + k];
    y0[t] = fmaxf(a, 0.f);
    __syncthreads();
    a = b2[t];
    for (int k = 0; k < DD; k++) a += y0[k] * w2[t * DD + k];
    y1[t] = fmaxf(a, 0.f);
    __syncthreads();
    float pv = y1[t] * w3[t];
    for (int off = 32; off; off >>= 1) pv += __shfl_down(pv, off);
    if ((t & 63) == 0) sred[t >> 6] = pv;
    __syncthreads();
    if (t == 0) out[b] = 1.f / (1.f + __expf(-(sred[0] + sred[1] + b3[0])));
}

extern "C" void kernel_launch(void* const* d_in, const int* in_sizes, int n_in,
                              void* d_out, int out_size, void* d_ws, size_t ws_size,
                              hipStream_t stream) {
    (void)in_sizes; (void)n_in; (void)out_size; (void)ws_size;
    const float* x     = (const float*)d_in[0];
    const float* adj1  = (const float*)d_in[1];
    const float* adj2  = (const float*)d_in[2];
    const float* valid = (const float*)d_in[3];
    const float* Ew    = (const float*)d_in[4];
    const float* gW    = (const float*)d_in[5];
    const float* gb    = (const float*)d_in[6];
    const float* gA    = (const float*)d_in[7];
    const float* gatew = (const float*)d_in[8];
    const float* gateb = (const float*)d_in[9];
    const float* w0 = (const float*)d_in[10]; const float* b0 = (const float*)d_in[11];
    const float* w1 = (const float*)d_in[12]; const float* b1 = (const float*)d_in[13];
    const float* w2 = (const float*)d_in[14]; const float* b2 = (const float*)d_in[15];
    const float* w3 = (const float*)d_in[16]; const float* b3 = (const float*)d_in[17];
    float* out = (float*)d_out;

    char* p = (char*)d_ws;
    float* rsr  = (float*)p; p += 2 * BN * 4;
    float* cfb  = (float*)p; p += 2 * BN * 4;
    float* partb = (float*)p; p += (size_t)NB * 8 * 128 * 4;
    half_t* h16   = (half_t*)p; p += BND * 2;
    half_t* hbr16 = (half_t*)p; p += BND * 2;
    half_t* hbrF  = (half_t*)p; p += BND * 2;
    half_t* hSF   = (half_t*)p; p += BND * 2;
    half_t* hbrT  = (half_t*)p; p += BND * 2;       // [16 b][128 d][1024 i]
    half_t* hbrsF = (half_t*)p; p += 2 * BND * 2;   // B-frag order, rsr-scaled hbr
    half_t* zf    = (half_t*)p; p += 2 * BND * 2;   // layer outputs, row-major
    half_t* zFA   = (half_t*)p; p += 2 * BND * 2;   // hop buffers, B-frag order
    half_t* zFB   = (half_t*)p; p += 2 * BND * 2;
    unsigned short* mask16 = (unsigned short*)p; p += (size_t)2 * BN * 64 * 2;
    half_t* DmF  = (half_t*)p; p += (size_t)2 * BN * 1024 * 2;   // 64 MiB A-frag D
    half_t* Wf16 = (half_t*)p; p += (size_t)4 * 128 * 128 * 2;
    half_t* ST16 = (half_t*)p; p += (size_t)4 * 128 * 128 * 2;
    half_t* EwF  = (half_t*)p; p += (size_t)128 * 128 * 2;

    k_cast<<<320, 256, 0, stream>>>(gW, gA, Ew, Wf16, ST16, EwF);
    k_emb<<<512, 256, 0, stream>>>(x, EwF, h16);
    k_mask<<<8192, 256, 0, stream>>>(adj1, adj2, mask16);

    for (int k = 0; k < 4; k++) {
        int nhop = k + 1;
        const half_t* pa = k ? (zf + BND) : h16;
        const half_t* pb = k ? zf : nullptr;
        k_proj<<<512, 256, 0, stream>>>(pa, pb, Wf16 + (size_t)k * 16384, gb + k * 128,
                                        ST16 + (size_t)k * 16384, hbr16, hbrT, hbrF, hSF);
        k_E<<<dim3(64, NB), 256, 0, stream>>>(hSF, hbrF, mask16, hbrT, DmF, rsr, hbrsF);
        // hop 1 (gate computed in-kernel)
        if (nhop == 1) {
            k_azd<<<512, 512, 0, stream>>>(DmF, rsr, hbrsF, hbr16, gatew + k * 256, gateb + k,
                                           cfb, zf, (half_t*)nullptr, 4);
        } else {
            k_azd<<<512, 512, 0, stream>>>(DmF, rsr, hbrsF, hbr16, gatew + k * 256, gateb + k,
                                           cfb, (half_t*)nullptr, zFA, 3);
        }
        const half_t* srcF = zFA;
        for (int hop = 2; hop <= nhop; hop++) {
            if (hop == nhop) {
                k_azd<<<512, 512, 0, stream>>>(DmF, rsr, srcF, hbr16, gatew + k * 256, gateb + k,
                                               cfb, zf, (half_t*)nullptr, 2);
            } else {
                half_t* dF = (hop & 1) ? zFA : zFB;
                k_azd<<<512, 512, 0, stream>>>(DmF, rsr, srcF, hbr16, gatew + k * 256, gateb + k,
                                               cfb, (half_t*)nullptr, dF, 1);
                srcF = dF;
            }
        }
    }
    k_pool<<<dim3(8, NB), 256, 0, stream>>>(zf + BND, zf, valid, partb);
    k_mlp<<<16, 128, 0, stream>>>(partb, valid, w0, b0, w1, b1, w2, b2, w3, b3, out);
}

// Round 13
// 598.891 us; speedup vs baseline: 1.0600x; 1.0600x over previous
//
#include <hip/hip_runtime.h>

typedef _Float16 half_t;
typedef _Float16 half8 __attribute__((ext_vector_type(8)));
typedef float floatx4 __attribute__((ext_vector_type(4)));

#define MFMA(a,b,c) __builtin_amdgcn_mfma_f32_16x16x32_f16(a,b,c,0,0,0)

#define NB 16
#define NLEN 1024
#define DD 128
#define BN (NB*NLEN)                       // 16384 rows per branch
#define BND ((size_t)NB*NLEN*DD)
#define EMP 1044                           // emS row stride

// ---------------- weight casts: gW->Wf16, gA+gA^T->ST16, Ew->EwF
__global__ __launch_bounds__(256)
void k_cast(const float* __restrict__ gW, const float* __restrict__ gA,
            const float* __restrict__ Ew,
            half_t* __restrict__ Wf, half_t* __restrict__ STf, half_t* __restrict__ EwF) {
    int i = blockIdx.x * 256 + threadIdx.x;
    if (i < 65536) {
        Wf[i] = (half_t)gW[i];
        int base = i & ~16383;
        int lrem = i & 16383;
        int d = lrem >> 7, e = lrem & 127;
        STf[base + (e << 7) + d] = (half_t)(gA[i] + gA[base + (e << 7) + d]);
    } else {
        int j = i - 65536;
        EwF[j] = (half_t)Ew[j];
    }
}

// ---------------- embed as MFMA GEMM: h16 = f16(x) @ EwF^T
__global__ __launch_bounds__(256)
void k_emb(const float* __restrict__ x, const half_t* __restrict__ EwF,
           half_t* __restrict__ h16) {
    __shared__ half_t htile[32 * 136];
    __shared__ half_t otile[32 * 136];
    int g = blockIdx.x * 32;
    int t = threadIdx.x;
    int w = t >> 6, l = t & 63, q = l >> 4, l15 = l & 15;
#pragma unroll
    for (int v = 0; v < 2; v++) {
        int idx = v * 256 + t; int r = idx >> 4, c8 = (idx & 15) * 8;
        const float* xp = &x[(size_t)(g + r) * DD + c8];
        float4 f0 = *(const float4*)xp;
        float4 f1 = *(const float4*)(xp + 4);
        half8 va;
        va[0] = (half_t)f0.x; va[1] = (half_t)f0.y; va[2] = (half_t)f0.z; va[3] = (half_t)f0.w;
        va[4] = (half_t)f1.x; va[5] = (half_t)f1.y; va[6] = (half_t)f1.z; va[7] = (half_t)f1.w;
        *(half8*)&htile[r * 136 + c8] = va;
    }
    __syncthreads();
    int rowh = (w & 1) * 16;
    int c0 = (w >> 1) * 4;
    half8 a1[4];
#pragma unroll
    for (int kc = 0; kc < 4; kc++) a1[kc] = *(const half8*)&htile[(rowh + l15) * 136 + kc * 32 + q * 8];
#pragma unroll
    for (int cc = 0; cc < 4; cc++) {
        int col = (c0 + cc) * 16 + l15;
        floatx4 a = {0.f, 0.f, 0.f, 0.f};
#pragma unroll
        for (int kc = 0; kc < 4; kc++) {
            half8 bf = *(const half8*)&EwF[((size_t)col << 7) + kc * 32 + q * 8];
            a = MFMA(a1[kc], bf, a);
        }
#pragma unroll
        for (int r = 0; r < 4; r++)
            otile[(rowh + q * 4 + r) * 136 + col] = (half_t)a[r];
    }
    __syncthreads();
#pragma unroll
    for (int v = 0; v < 2; v++) {
        int idx = v * 256 + t; int r = idx >> 4, c8 = (idx & 15) * 8;
        *(half8*)&h16[((size_t)(g + r) << 7) + c8] = *(const half8*)&otile[r * 136 + c8];
    }
}

// ---------------- adjacency bitmask build, coalesced via LDS bounce
__global__ __launch_bounds__(256)
void k_mask(const float* __restrict__ adj1, const float* __restrict__ adj2,
            unsigned short* __restrict__ mask16) {
    __shared__ float ls[4][1024];              // 16 KiB
    int tid = threadIdx.x;
    int bid = blockIdx.x;
    int w = tid >> 6, l = tid & 63;
    int R = bid * 4 + w;
    int br = R >> 14, nb = R & 16383;
    const float* arow = (br ? adj2 : adj1) + (size_t)nb * 1024;
#pragma unroll
    for (int c = 0; c < 4; c++)
        *(float4*)&ls[w][c * 256 + l * 4] = *(const float4*)&arow[c * 256 + l * 4];
    __syncthreads();
    unsigned m = 0u;
#pragma unroll
    for (int c = 0; c < 4; c++) {
        float4 v = *(const float4*)&ls[w][l * 16 + c * 4];
        m |= (v.x > 0.f ? 1u : 0u) << (c * 4);
        m |= (v.y > 0.f ? 1u : 0u) << (c * 4 + 1);
        m |= (v.z > 0.f ? 1u : 0u) << (c * 4 + 2);
        m |= (v.w > 0.f ? 1u : 0u) << (c * 4 + 3);
    }
    mask16[(size_t)R * 64 + l] = (unsigned short)m;
}

// ---------------- proj (MFMA): in = pa - pb (f16); hbr = in@W^T + b ; hS = hbr@S
__global__ __launch_bounds__(256)
void k_proj(const half_t* __restrict__ pa, const half_t* __restrict__ pb,
            const half_t* __restrict__ Wf, const float* __restrict__ bias,
            const half_t* __restrict__ STf,
            half_t* __restrict__ hbr16, half_t* __restrict__ hbrT,
            half_t* __restrict__ hbrF, half_t* __restrict__ hSF) {
    __shared__ half_t htile[32 * 136];
    __shared__ half_t hbtile[32 * 136];
    int g = blockIdx.x * 32;
    int t = threadIdx.x;
    int w = t >> 6, l = t & 63, q = l >> 4, l15 = l & 15;
#pragma unroll
    for (int v = 0; v < 2; v++) {
        int idx = v * 256 + t; int r = idx >> 4, c8 = (idx & 15) * 8;
        half8 va = *(const half8*)&pa[((size_t)(g + r) << 7) + c8];
        if (pb) {
            half8 vb = *(const half8*)&pb[((size_t)(g + r) << 7) + c8];
            va = va - vb;
        }
        *(half8*)&htile[r * 136 + c8] = va;
    }
    __syncthreads();
    int rowh = (w & 1) * 16;
    int c0 = (w >> 1) * 4;
    half8 a1[4];
#pragma unroll
    for (int kc = 0; kc < 4; kc++) a1[kc] = *(const half8*)&htile[(rowh + l15) * 136 + kc * 32 + q * 8];
    floatx4 acc[4];
#pragma unroll
    for (int cc = 0; cc < 4; cc++) {
        int col = (c0 + cc) * 16 + l15;
        floatx4 a = {0.f, 0.f, 0.f, 0.f};
#pragma unroll
        for (int kc = 0; kc < 4; kc++) {
            half8 bf = *(const half8*)&Wf[((size_t)col << 7) + kc * 32 + q * 8];
            a = MFMA(a1[kc], bf, a);
        }
        float bv = bias[col];
        a.x += bv; a.y += bv; a.z += bv; a.w += bv;
        acc[cc] = a;
    }
#pragma unroll
    for (int cc = 0; cc < 4; cc++) {
        int col = (c0 + cc) * 16 + l15;
#pragma unroll
        for (int r = 0; r < 4; r++)
            hbtile[(rowh + q * 4 + r) * 136 + col] = (half_t)acc[cc][r];
    }
    __syncthreads();
    half8 a2[4];
#pragma unroll
    for (int kc = 0; kc < 4; kc++) a2[kc] = *(const half8*)&hbtile[(rowh + l15) * 136 + kc * 32 + q * 8];
#pragma unroll
    for (int cc = 0; cc < 4; cc++) {
        int col = (c0 + cc) * 16 + l15;
        floatx4 a = {0.f, 0.f, 0.f, 0.f};
#pragma unroll
        for (int kc = 0; kc < 4; kc++) {
            half8 bf = *(const half8*)&STf[((size_t)col << 7) + kc * 32 + q * 8];
            a = MFMA(a2[kc], bf, a);
        }
        acc[cc] = a;
    }
    __syncthreads();
#pragma unroll
    for (int cc = 0; cc < 4; cc++) {
        int col = (c0 + cc) * 16 + l15;
#pragma unroll
        for (int r = 0; r < 4; r++) htile[(rowh + q * 4 + r) * 136 + col] = (half_t)acc[cc][r];
    }
    __syncthreads();
#pragma unroll
    for (int v = 0; v < 2; v++) {
        int idx = v * 256 + t; int r = idx >> 4, c8 = (idx & 15) * 8;
        *(half8*)&hbr16[((size_t)(g + r) << 7) + c8] = *(const half8*)&hbtile[r * 136 + c8];
    }
    // transposed hbr: hbrT[b][d][i]
    {
        int b_ = g >> 10, gi = g & 1023;
        int d = t >> 1, hh = t & 1;
        half8 r0, r1;
#pragma unroll
        for (int e = 0; e < 8; e++) {
            r0[e] = hbtile[(hh * 16 + e) * 136 + d];
            r1[e] = hbtile[(hh * 16 + 8 + e) * 136 + d];
        }
        half_t* op = hbrT + ((size_t)b_ * 128 + d) * 1024 + gi + hh * 16;
        *(half8*)op = r0;
        *(half8*)(op + 8) = r1;
    }
#pragma unroll
    for (int v = 0; v < 2; v++) {
        int fi = v * 256 + t;
        int g2 = fi >> 8, kc = (fi >> 6) & 3, li = fi & 63;
        int src = (g2 * 16 + (li & 15)) * 136 + kc * 32 + (li >> 4) * 8;
        size_t dst = (((size_t)(blockIdx.x * 2 + g2) * 4 + kc) << 10) + li * 8;
        *(half8*)&hbrF[dst] = *(const half8*)&hbtile[src];
        *(half8*)&hSF[dst]  = *(const half8*)&htile[src];
    }
}

// ---------------- E: em strip (MFMA) -> DENSE D rows (mask?exp:0), rsr, hbrsT.
__global__ __launch_bounds__(256)
void k_E(const half_t* __restrict__ hSF, const half_t* __restrict__ hbrF,
         const unsigned short* __restrict__ mask16, const half_t* __restrict__ hbrT,
         half_t* __restrict__ Dm, float* __restrict__ rsr, half_t* __restrict__ hbrsT) {
    int hw = blockIdx.y * 64 + blockIdx.x;
    int wk = (hw & 7) * 128 + (hw >> 3);
    int b = wk >> 6, s = wk & 63;              // 64 strips of 16 rows per batch
    int t = threadIdx.x, w = t >> 6, l = t & 63, q = l >> 4, l15 = l & 15;
    __shared__ half_t emS[16 * EMP];
    __shared__ float rsS[2][16];
    size_t Gb = (size_t)b * 64;
    half8 A[4];
#pragma unroll
    for (int kc = 0; kc < 4; kc++)
        A[kc] = *(const half8*)&hSF[(((Gb + s) * 4 + kc) << 10) + l * 8];
#pragma unroll 4
    for (int cg = 0; cg < 16; cg++) {
        int c0 = w * 256 + cg * 16;
        floatx4 a = {0.f, 0.f, 0.f, 0.f};
#pragma unroll
        for (int kc = 0; kc < 4; kc++) {
            half8 bf = *(const half8*)&hbrF[(((Gb + w * 16 + cg) * 4 + kc) << 10) + l * 8];
            a = MFMA(A[kc], bf, a);
        }
#pragma unroll
        for (int r = 0; r < 4; r++)
            emS[(q * 4 + r) * EMP + c0 + l15] = (half_t)a[r];
    }
    __syncthreads();
    const float CN = 0.000335462627903f;       // exp(-8)
#pragma unroll
    for (int tt = 0; tt < 8; tt++) {
        int task = tt * 4 + w;                 // 32 tasks: (rl, br)
        int rl = task >> 1, br = task & 1;
        size_t R = ((size_t)br << 14) + (size_t)b * 1024 + s * 16 + rl;
        unsigned mv = (unsigned)mask16[R * 64 + l];
        half8 e0 = *(const half8*)&emS[rl * EMP + l * 16];
        half8 e1 = *(const half8*)&emS[rl * EMP + l * 16 + 8];
        half8 o0, o1;
        float rs = 0.f;
#pragma unroll
        for (int c2 = 0; c2 < 8; c2++) {
            float v0 = ((mv >> c2) & 1u) ? __expf((float)e0[c2] - 8.f) : 0.f;
            float v1 = ((mv >> (c2 + 8)) & 1u) ? __expf((float)e1[c2] - 8.f) : 0.f;
            o0[c2] = (half_t)v0; o1[c2] = (half_t)v1;
            rs += v0 + v1;
        }
        *(half8*)&Dm[R * 1024 + l * 16] = o0;
        *(half8*)&Dm[R * 1024 + l * 16 + 8] = o1;
        int cn = __popc(mv);
        rs += __shfl_xor(rs, 1); rs += __shfl_xor(rs, 2);
        rs += __shfl_xor(rs, 4); rs += __shfl_xor(rs, 8);
        rs += __shfl_xor(rs, 16); rs += __shfl_xor(rs, 32);
        cn += __shfl_xor(cn, 1); cn += __shfl_xor(cn, 2);
        cn += __shfl_xor(cn, 4); cn += __shfl_xor(cn, 8);
        cn += __shfl_xor(cn, 16); cn += __shfl_xor(cn, 32);
        if (l == 0) {
            float rv = 1.f / (rs + (1024.f - (float)cn) * CN);
            rsr[R] = rv;
            rsS[br][rl] = rv;
        }
    }
    __syncthreads();
    // hbrsT[(br,b)][d][i] = rsr[i] * hbrT[b][d][i]
    {
        int d = t >> 1, br = t & 1;
        const half_t* hp = hbrT + ((size_t)b * 128 + d) * 1024 + s * 16;
        half8 a0 = *(const half8*)hp, a1 = *(const half8*)(hp + 8);
        half8 r0, r1;
#pragma unroll
        for (int e = 0; e < 8; e++) {
            r0[e] = (half_t)((float)a0[e] * rsS[br][e]);
            r1[e] = (half_t)((float)a1[e] * rsS[br][8 + e]);
        }
        half_t* op = hbrsT + (((size_t)((br << 4) + b)) * 128 + d) * 1024 + s * 16;
        *(half8*)op = r0;
        *(half8*)(op + 8) = r1;
    }
}

// ---------------- dense az GEMM, staged (§5), BM=64, 2 blocks/CU,
// 2-TILE-DEEP register prefetch (named sets, hand-unrolled x2 — each LDS
// write has >=2 compute phases of latency cover for the HBM/L3 Dm stream).
__global__ __launch_bounds__(512)
void k_azd(const half_t* __restrict__ Dm, const float* __restrict__ rsr,
           const half_t* __restrict__ BT, const half_t* __restrict__ hbr16,
           const float* __restrict__ gw, const float* __restrict__ gb_,
           float* __restrict__ cfb, half_t* __restrict__ outR, half_t* __restrict__ outT,
           int mode) {
    __shared__ union {
        struct { half_t A[2][64][72]; half_t B[2][128][72]; } s;
        half_t az[64][136];
    } sm;
    int t = threadIdx.x, w = t >> 6, l = t & 63, q = l >> 4, l15 = l & 15;
    int wi = w & 3, wd = w >> 2;               // i-group (16 rows) / d-half (64)
    int bid = blockIdx.x;
    int slice = bid & 31, tile = bid >> 5;     // 16 tiles of 64 rows
    int br = slice & 1, b = slice >> 1;
    int c = (br << 4) + b;
    int i0 = tile * 64;
    const half_t* Dp = Dm + ((size_t)c << 20) + (size_t)i0 * 1024;
    const half_t* Bp = BT + ((size_t)c << 17);
    int ar = t >> 3, ac = (t & 7) * 8;         // staging coords
    // two register prefetch sets (A=even tiles, B=odd tiles)
    half8 raA, rbA0, rbA1, raB, rbB0, rbB1;
    raA  = *(const half8*)&Dp[(size_t)ar * 1024 + ac];
    rbA0 = *(const half8*)&Bp[(size_t)ar * 1024 + ac];
    rbA1 = *(const half8*)&Bp[(size_t)(ar + 64) * 1024 + ac];
    raB  = *(const half8*)&Dp[(size_t)ar * 1024 + 64 + ac];
    rbB0 = *(const half8*)&Bp[(size_t)ar * 1024 + 64 + ac];
    rbB1 = *(const half8*)&Bp[(size_t)(ar + 64) * 1024 + 64 + ac];
    *(half8*)&sm.s.A[0][ar][ac] = raA;
    *(half8*)&sm.s.B[0][ar][ac] = rbA0;
    *(half8*)&sm.s.B[0][ar + 64][ac] = rbA1;
    __syncthreads();
    floatx4 acc[4] = {};
    for (int kt = 0; kt < 16; kt += 2) {
        // ---- even tile kt (LDS buf 0); issue T(kt+2) into set A
        if (kt < 14) {
            int ko = (kt + 2) * 64;
            raA  = *(const half8*)&Dp[(size_t)ar * 1024 + ko + ac];
            rbA0 = *(const half8*)&Bp[(size_t)ar * 1024 + ko + ac];
            rbA1 = *(const half8*)&Bp[(size_t)(ar + 64) * 1024 + ko + ac];
        }
#pragma unroll
        for (int kk = 0; kk < 2; kk++) {
            half8 af = *(const half8*)&sm.s.A[0][wi * 16 + l15][kk * 32 + q * 8];
#pragma unroll
            for (int nf = 0; nf < 4; nf++) {
                half8 bf = *(const half8*)&sm.s.B[0][wd * 64 + nf * 16 + l15][kk * 32 + q * 8];
                acc[nf] = MFMA(af, bf, acc[nf]);
            }
        }
        __syncthreads();
        // write T(kt+1) from set B -> LDS buf 1
        *(half8*)&sm.s.A[1][ar][ac] = raB;
        *(half8*)&sm.s.B[1][ar][ac] = rbB0;
        *(half8*)&sm.s.B[1][ar + 64][ac] = rbB1;
        __syncthreads();
        // ---- odd tile kt+1 (LDS buf 1); issue T(kt+3) into set B
        if (kt + 1 < 14) {
            int ko = (kt + 3) * 64;
            raB  = *(const half8*)&Dp[(size_t)ar * 1024 + ko + ac];
            rbB0 = *(const half8*)&Bp[(size_t)ar * 1024 + ko + ac];
            rbB1 = *(const half8*)&Bp[(size_t)(ar + 64) * 1024 + ko + ac];
        }
#pragma unroll
        for (int kk = 0; kk < 2; kk++) {
            half8 af = *(const half8*)&sm.s.A[1][wi * 16 + l15][kk * 32 + q * 8];
#pragma unroll
            for (int nf = 0; nf < 4; nf++) {
                half8 bf = *(const half8*)&sm.s.B[1][wd * 64 + nf * 16 + l15][kk * 32 + q * 8];
                acc[nf] = MFMA(af, bf, acc[nf]);
            }
        }
        __syncthreads();
        if (kt + 2 < 16) {
            // write T(kt+2) from set A -> LDS buf 0
            *(half8*)&sm.s.A[0][ar][ac] = raA;
            *(half8*)&sm.s.B[0][ar][ac] = rbA0;
            *(half8*)&sm.s.B[0][ar + 64][ac] = rbA1;
            __syncthreads();
        }
    }
    // acc -> az tile (all compute synced; az aliases stage buffers)
#pragma unroll
    for (int nf = 0; nf < 4; nf++)
#pragma unroll
        for (int r = 0; r < 4; r++)
            sm.az[wi * 16 + q * 4 + r][wd * 64 + nf * 16 + l15] = (half_t)acc[nf][r];
    __syncthreads();
#pragma unroll
    for (int it = 0; it < 2; it++) {
        int iloc = it * 32 + (t >> 4);         // 32 rows/pass, 16 lanes per row
        int i = i0 + iloc;
        int nb = b * 1024 + i;
        int R = c * 1024 + i;
        half8 az8 = *(const half8*)&sm.az[iloc][l15 * 8];
        half8 hv8 = *(const half8*)&hbr16[((size_t)nb << 7) + l15 * 8];
        float av[8], hv[8];
#pragma unroll
        for (int d = 0; d < 8; d++) {
            av[d] = fmaxf((float)az8[d], 0.f);
            hv[d] = (float)hv8[d];
        }
        float cf;
        if (mode >= 3) {
            const float* g1 = gw + l15 * 8;
            const float* g2 = gw + 128 + l15 * 8;
            float dp = 0.f;
#pragma unroll
            for (int d = 0; d < 8; d++) dp += hv[d] * g1[d] + av[d] * g2[d];
            dp += __shfl_xor(dp, 1); dp += __shfl_xor(dp, 2);
            dp += __shfl_xor(dp, 4); dp += __shfl_xor(dp, 8);
            cf = 1.f / (1.f + __expf(-(dp + gb_[0])));
            if (l15 == 0) cfb[R] = cf;
        } else {
            cf = cfb[R];
        }
        if (mode == 2 || mode == 4) {
            half8 o;
#pragma unroll
            for (int d = 0; d < 8; d++) o[d] = (half_t)(cf * hv[d] + (1.f - cf) * av[d]);
            *(half8*)&outR[(size_t)R * DD + l15 * 8] = o;
        } else {
            float sc = rsr[R];
#pragma unroll
            for (int d = 0; d < 8; d++)
                sm.az[iloc][l15 * 8 + d] = (half_t)(sc * (cf * hv[d] + (1.f - cf) * av[d]));
        }
    }
    if (mode == 1 || mode == 3) {
        __syncthreads();
        int d = t & 127, g4 = t >> 7;          // 4 i-chunks of 16
        half_t* op = outT + ((size_t)c * 128 + d) * 1024 + i0 + g4 * 16;
        half8 r0, r1;
#pragma unroll
        for (int e = 0; e < 8; e++) {
            r0[e] = sm.az[g4 * 16 + e][d];
            r1[e] = sm.az[g4 * 16 + 8 + e][d];
        }
        *(half8*)op = r0;
        *(half8*)(op + 8) = r1;
    }
}

// ---------------- partial masked pool of (z2 - z1), f16 inputs
__global__ __launch_bounds__(256)
void k_pool(const half_t* __restrict__ z2, const half_t* __restrict__ z1,
            const float* __restrict__ valid, float* __restrict__ part) {
    int b = blockIdx.y, s = blockIdx.x;
    int t = threadIdx.x, d = t & 127, hf = t >> 7;
    __shared__ float red[128];
    float acc = 0.f;
    int nbase = s * 128 + hf * 64;
    for (int n = nbase; n < nbase + 64; n++) {
        size_t gi = ((size_t)(b * 1024 + n) << 7) + d;
        acc += ((float)z2[gi] - (float)z1[gi]) * valid[b * 1024 + n];
    }
    if (hf) red[d] = acc;
    __syncthreads();
    if (!hf) part[(b * 8 + s) * 128 + d] = acc + red[d];
}

// ---------------- final reduce + MLP head
__global__ __launch_bounds__(128)
void k_mlp(const float* __restrict__ part, const float* __restrict__ valid,
           const float* __restrict__ w0, const float* __restrict__ b0,
           const float* __restrict__ w1, const float* __restrict__ b1,
           const float* __restrict__ w2, const float* __restrict__ b2,
           const float* __restrict__ w3, const float* __restrict__ b3,
           float* __restrict__ out) {
    int b = blockIdx.x, t = threadIdx.x;
    __shared__ float y0[DD], y1[DD];
    __shared__ float sred[2];
    float vs = 0.f;
    for (int n = t; n < NLEN; n += 128) vs += valid[b * NLEN + n];
    for (int off = 32; off; off >>= 1) vs += __shfl_down(vs, off);
    if ((t & 63) == 0) sred[t >> 6] = vs;
    __syncthreads();
    float vsum = sred[0] + sred[1];
    float acc = 0.f;
#pragma unroll
    for (int s = 0; s < 8; s++) acc += part[(b * 8 + s) * 128 + t];
    y0[t] = acc / vsum;
    __syncthreads();
    float a = b0[t];
    for (int k = 0; k < DD; k++) a += y0[k] * w0[t * DD + k];
    y1[t] = fmaxf(a, 0.f);
    __syncthreads();
    a = b1[t];
    for (int k = 0; k < DD; k++) a += y1[k] * w1[t * DD + k];
    y0[t] = fmaxf(a, 0.f);
    __syncthreads();
    a = b2[t];
    for (int k = 0; k < DD; k++) a += y0[k] * w2[t * DD + k];
    y1[t] = fmaxf(a, 0.f);
    __syncthreads();
    float pv = y1[t] * w3[t];
    for (int off = 32; off; off >>= 1) pv += __shfl_down(pv, off);
    if ((t & 63) == 0) sred[t >> 6] = pv;
    __syncthreads();
    if (t == 0) out[b] = 1.f / (1.f + __expf(-(sred[0] + sred[1] + b3[0])));
}

extern "C" void kernel_launch(void* const* d_in, const int* in_sizes, int n_in,
                              void* d_out, int out_size, void* d_ws, size_t ws_size,
                              hipStream_t stream) {
    (void)in_sizes; (void)n_in; (void)out_size; (void)ws_size;
    const float* x     = (const float*)d_in[0];
    const float* adj1  = (const float*)d_in[1];
    const float* adj2  = (const float*)d_in[2];
    const float* valid = (const float*)d_in[3];
    const float* Ew    = (const float*)d_in[4];
    const float* gW    = (const float*)d_in[5];
    const float* gb    = (const float*)d_in[6];
    const float* gA    = (const float*)d_in[7];
    const float* gatew = (const float*)d_in[8];
    const float* gateb = (const float*)d_in[9];
    const float* w0 = (const float*)d_in[10]; const float* b0 = (const float*)d_in[11];
    const float* w1 = (const float*)d_in[12]; const float* b1 = (const float*)d_in[13];
    const float* w2 = (const float*)d_in[14]; const float* b2 = (const float*)d_in[15];
    const float* w3 = (const float*)d_in[16]; const float* b3 = (const float*)d_in[17];
    float* out = (float*)d_out;

    char* p = (char*)d_ws;
    float* rsr  = (float*)p; p += 2 * BN * 4;
    float* cfb  = (float*)p; p += 2 * BN * 4;
    float* partb = (float*)p; p += (size_t)NB * 8 * 128 * 4;
    half_t* h16   = (half_t*)p; p += BND * 2;
    half_t* hbr16 = (half_t*)p; p += BND * 2;
    half_t* hbrF  = (half_t*)p; p += BND * 2;
    half_t* hSF   = (half_t*)p; p += BND * 2;
    half_t* hbrT  = (half_t*)p; p += BND * 2;       // [16 b][128 d][1024 i]
    half_t* hbrsT = (half_t*)p; p += 2 * BND * 2;   // [(br,b)][128 d][1024 i]
    half_t* zf    = (half_t*)p; p += 2 * BND * 2;   // layer outputs, row-major
    half_t* zTA   = (half_t*)p; p += 2 * BND * 2;   // hop buffers, transposed
    half_t* zTB   = (half_t*)p; p += 2 * BND * 2;
    unsigned short* mask16 = (unsigned short*)p; p += (size_t)2 * BN * 64 * 2;
    half_t* Dm   = (half_t*)p; p += (size_t)2 * BN * 1024 * 2;   // 64 MiB dense att
    half_t* Wf16 = (half_t*)p; p += (size_t)4 * 128 * 128 * 2;
    half_t* ST16 = (half_t*)p; p += (size_t)4 * 128 * 128 * 2;
    half_t* EwF  = (half_t*)p; p += (size_t)128 * 128 * 2;

    k_cast<<<320, 256, 0, stream>>>(gW, gA, Ew, Wf16, ST16, EwF);
    k_emb<<<512, 256, 0, stream>>>(x, EwF, h16);
    k_mask<<<8192, 256, 0, stream>>>(adj1, adj2, mask16);

    for (int k = 0; k < 4; k++) {
        int nhop = k + 1;
        const half_t* pa = k ? (zf + BND) : h16;
        const half_t* pb = k ? zf : nullptr;
        k_proj<<<512, 256, 0, stream>>>(pa, pb, Wf16 + (size_t)k * 16384, gb + k * 128,
                                        ST16 + (size_t)k * 16384, hbr16, hbrT, hbrF, hSF);
        k_E<<<dim3(64, NB), 256, 0, stream>>>(hSF, hbrF, mask16, hbrT, Dm, rsr, hbrsT);
        // hop 1 (gate computed in-kernel)
        if (nhop == 1) {
            k_azd<<<512, 512, 0, stream>>>(Dm, rsr, hbrsT, hbr16, gatew + k * 256, gateb + k,
                                           cfb, zf, (half_t*)nullptr, 4);
        } else {
            k_azd<<<512, 512, 0, stream>>>(Dm, rsr, hbrsT, hbr16, gatew + k * 256, gateb + k,
                                           cfb, (half_t*)nullptr, zTA, 3);
        }
        const half_t* srcT = zTA;
        for (int hop = 2; hop <= nhop; hop++) {
            if (hop == nhop) {
                k_azd<<<512, 512, 0, stream>>>(Dm, rsr, srcT, hbr16, gatew + k * 256, gateb + k,
                                               cfb, zf, (half_t*)nullptr, 2);
            } else {
                half_t* dT = (hop & 1) ? zTA : zTB;
                k_azd<<<512, 512, 0, stream>>>(Dm, rsr, srcT, hbr16, gatew + k * 256, gateb + k,
                                               cfb, (half_t*)nullptr, dT, 1);
                srcT = dT;
            }
        }
    }
    k_pool<<<dim3(8, NB), 256, 0, stream>>>(zf + BND, zf, valid, partb);
    k_mlp<<<16, 128, 0, stream>>>(partb, valid, w0, b0, w1, b1, w2, b2, w3, b3, out);
}

// Round 14
// 586.311 us; speedup vs baseline: 1.0828x; 1.0215x over previous
//
#include <hip/hip_runtime.h>

typedef _Float16 half_t;
typedef _Float16 half8 __attribute__((ext_vector_type(8)));
typedef float floatx4 __attribute__((ext_vector_type(4)));

#define MFMA(a,b,c) __builtin_amdgcn_mfma_f32_16x16x32_f16(a,b,c,0,0,0)

#define NB 16
#define NLEN 1024
#define DD 128
#define BN (NB*NLEN)                       // 16384 rows per branch
#define BND ((size_t)NB*NLEN*DD)
#define EMP 1044                           // emS row stride

// ---------------- weight casts: gW->Wf16, gA+gA^T->ST16, Ew->EwF
__global__ __launch_bounds__(256)
void k_cast(const float* __restrict__ gW, const float* __restrict__ gA,
            const float* __restrict__ Ew,
            half_t* __restrict__ Wf, half_t* __restrict__ STf, half_t* __restrict__ EwF) {
    int i = blockIdx.x * 256 + threadIdx.x;
    if (i < 65536) {
        Wf[i] = (half_t)gW[i];
        int base = i & ~16383;
        int lrem = i & 16383;
        int d = lrem >> 7, e = lrem & 127;
        STf[base + (e << 7) + d] = (half_t)(gA[i] + gA[base + (e << 7) + d]);
    } else {
        int j = i - 65536;
        EwF[j] = (half_t)Ew[j];
    }
}

// ---------------- embed as MFMA GEMM: h16 = f16(x) @ EwF^T
__global__ __launch_bounds__(256)
void k_emb(const float* __restrict__ x, const half_t* __restrict__ EwF,
           half_t* __restrict__ h16) {
    __shared__ half_t htile[32 * 136];
    __shared__ half_t otile[32 * 136];
    int g = blockIdx.x * 32;
    int t = threadIdx.x;
    int w = t >> 6, l = t & 63, q = l >> 4, l15 = l & 15;
#pragma unroll
    for (int v = 0; v < 2; v++) {
        int idx = v * 256 + t; int r = idx >> 4, c8 = (idx & 15) * 8;
        const float* xp = &x[(size_t)(g + r) * DD + c8];
        float4 f0 = *(const float4*)xp;
        float4 f1 = *(const float4*)(xp + 4);
        half8 va;
        va[0] = (half_t)f0.x; va[1] = (half_t)f0.y; va[2] = (half_t)f0.z; va[3] = (half_t)f0.w;
        va[4] = (half_t)f1.x; va[5] = (half_t)f1.y; va[6] = (half_t)f1.z; va[7] = (half_t)f1.w;
        *(half8*)&htile[r * 136 + c8] = va;
    }
    __syncthreads();
    int rowh = (w & 1) * 16;
    int c0 = (w >> 1) * 4;
    half8 a1[4];
#pragma unroll
    for (int kc = 0; kc < 4; kc++) a1[kc] = *(const half8*)&htile[(rowh + l15) * 136 + kc * 32 + q * 8];
#pragma unroll
    for (int cc = 0; cc < 4; cc++) {
        int col = (c0 + cc) * 16 + l15;
        floatx4 a = {0.f, 0.f, 0.f, 0.f};
#pragma unroll
        for (int kc = 0; kc < 4; kc++) {
            half8 bf = *(const half8*)&EwF[((size_t)col << 7) + kc * 32 + q * 8];
            a = MFMA(a1[kc], bf, a);
        }
#pragma unroll
        for (int r = 0; r < 4; r++)
            otile[(rowh + q * 4 + r) * 136 + col] = (half_t)a[r];
    }
    __syncthreads();
#pragma unroll
    for (int v = 0; v < 2; v++) {
        int idx = v * 256 + t; int r = idx >> 4, c8 = (idx & 15) * 8;
        *(half8*)&h16[((size_t)(g + r) << 7) + c8] = *(const half8*)&otile[r * 136 + c8];
    }
}

// ---------------- adjacency bitmask build, coalesced via LDS bounce
__global__ __launch_bounds__(256)
void k_mask(const float* __restrict__ adj1, const float* __restrict__ adj2,
            unsigned short* __restrict__ mask16) {
    __shared__ float ls[4][1024];              // 16 KiB
    int tid = threadIdx.x;
    int bid = blockIdx.x;
    int w = tid >> 6, l = tid & 63;
    int R = bid * 4 + w;
    int br = R >> 14, nb = R & 16383;
    const float* arow = (br ? adj2 : adj1) + (size_t)nb * 1024;
#pragma unroll
    for (int c = 0; c < 4; c++)
        *(float4*)&ls[w][c * 256 + l * 4] = *(const float4*)&arow[c * 256 + l * 4];
    __syncthreads();
    unsigned m = 0u;
#pragma unroll
    for (int c = 0; c < 4; c++) {
        float4 v = *(const float4*)&ls[w][l * 16 + c * 4];
        m |= (v.x > 0.f ? 1u : 0u) << (c * 4);
        m |= (v.y > 0.f ? 1u : 0u) << (c * 4 + 1);
        m |= (v.z > 0.f ? 1u : 0u) << (c * 4 + 2);
        m |= (v.w > 0.f ? 1u : 0u) << (c * 4 + 3);
    }
    mask16[(size_t)R * 64 + l] = (unsigned short)m;
}

// ---------------- proj (MFMA): in = pa - pb (f16); hbr = in@W^T + b ; hS = hbr@S
__global__ __launch_bounds__(256)
void k_proj(const half_t* __restrict__ pa, const half_t* __restrict__ pb,
            const half_t* __restrict__ Wf, const float* __restrict__ bias,
            const half_t* __restrict__ STf,
            half_t* __restrict__ hbr16, half_t* __restrict__ hbrT,
            half_t* __restrict__ hbrF, half_t* __restrict__ hSF) {
    __shared__ half_t htile[32 * 136];
    __shared__ half_t hbtile[32 * 136];
    int g = blockIdx.x * 32;
    int t = threadIdx.x;
    int w = t >> 6, l = t & 63, q = l >> 4, l15 = l & 15;
#pragma unroll
    for (int v = 0; v < 2; v++) {
        int idx = v * 256 + t; int r = idx >> 4, c8 = (idx & 15) * 8;
        half8 va = *(const half8*)&pa[((size_t)(g + r) << 7) + c8];
        if (pb) {
            half8 vb = *(const half8*)&pb[((size_t)(g + r) << 7) + c8];
            va = va - vb;
        }
        *(half8*)&htile[r * 136 + c8] = va;
    }
    __syncthreads();
    int rowh = (w & 1) * 16;
    int c0 = (w >> 1) * 4;
    half8 a1[4];
#pragma unroll
    for (int kc = 0; kc < 4; kc++) a1[kc] = *(const half8*)&htile[(rowh + l15) * 136 + kc * 32 + q * 8];
    floatx4 acc[4];
#pragma unroll
    for (int cc = 0; cc < 4; cc++) {
        int col = (c0 + cc) * 16 + l15;
        floatx4 a = {0.f, 0.f, 0.f, 0.f};
#pragma unroll
        for (int kc = 0; kc < 4; kc++) {
            half8 bf = *(const half8*)&Wf[((size_t)col << 7) + kc * 32 + q * 8];
            a = MFMA(a1[kc], bf, a);
        }
        float bv = bias[col];
        a.x += bv; a.y += bv; a.z += bv; a.w += bv;
        acc[cc] = a;
    }
#pragma unroll
    for (int cc = 0; cc < 4; cc++) {
        int col = (c0 + cc) * 16 + l15;
#pragma unroll
        for (int r = 0; r < 4; r++)
            hbtile[(rowh + q * 4 + r) * 136 + col] = (half_t)acc[cc][r];
    }
    __syncthreads();
    half8 a2[4];
#pragma unroll
    for (int kc = 0; kc < 4; kc++) a2[kc] = *(const half8*)&hbtile[(rowh + l15) * 136 + kc * 32 + q * 8];
#pragma unroll
    for (int cc = 0; cc < 4; cc++) {
        int col = (c0 + cc) * 16 + l15;
        floatx4 a = {0.f, 0.f, 0.f, 0.f};
#pragma unroll
        for (int kc = 0; kc < 4; kc++) {
            half8 bf = *(const half8*)&STf[((size_t)col << 7) + kc * 32 + q * 8];
            a = MFMA(a2[kc], bf, a);
        }
        acc[cc] = a;
    }
    __syncthreads();
#pragma unroll
    for (int cc = 0; cc < 4; cc++) {
        int col = (c0 + cc) * 16 + l15;
#pragma unroll
        for (int r = 0; r < 4; r++) htile[(rowh + q * 4 + r) * 136 + col] = (half_t)acc[cc][r];
    }
    __syncthreads();
#pragma unroll
    for (int v = 0; v < 2; v++) {
        int idx = v * 256 + t; int r = idx >> 4, c8 = (idx & 15) * 8;
        *(half8*)&hbr16[((size_t)(g + r) << 7) + c8] = *(const half8*)&hbtile[r * 136 + c8];
    }
    // transposed hbr: hbrT[b][d][i]
    {
        int b_ = g >> 10, gi = g & 1023;
        int d = t >> 1, hh = t & 1;
        half8 r0, r1;
#pragma unroll
        for (int e = 0; e < 8; e++) {
            r0[e] = hbtile[(hh * 16 + e) * 136 + d];
            r1[e] = hbtile[(hh * 16 + 8 + e) * 136 + d];
        }
        half_t* op = hbrT + ((size_t)b_ * 128 + d) * 1024 + gi + hh * 16;
        *(half8*)op = r0;
        *(half8*)(op + 8) = r1;
    }
#pragma unroll
    for (int v = 0; v < 2; v++) {
        int fi = v * 256 + t;
        int g2 = fi >> 8, kc = (fi >> 6) & 3, li = fi & 63;
        int src = (g2 * 16 + (li & 15)) * 136 + kc * 32 + (li >> 4) * 8;
        size_t dst = (((size_t)(blockIdx.x * 2 + g2) * 4 + kc) << 10) + li * 8;
        *(half8*)&hbrF[dst] = *(const half8*)&hbtile[src];
        *(half8*)&hSF[dst]  = *(const half8*)&htile[src];
    }
}

// ---------------- E: em strip (MFMA, 2-deep prefetched hbrF loads) ->
// DENSE D rows (mask?exp:0, mask loads batch-prefetched), rsr, hbrsT.
__global__ __launch_bounds__(256)
void k_E(const half_t* __restrict__ hSF, const half_t* __restrict__ hbrF,
         const unsigned short* __restrict__ mask16, const half_t* __restrict__ hbrT,
         half_t* __restrict__ Dm, float* __restrict__ rsr, half_t* __restrict__ hbrsT) {
    int hw = blockIdx.y * 64 + blockIdx.x;
    int wk = (hw & 7) * 128 + (hw >> 3);
    int b = wk >> 6, s = wk & 63;              // 64 strips of 16 rows per batch
    int t = threadIdx.x, w = t >> 6, l = t & 63, q = l >> 4, l15 = l & 15;
    __shared__ half_t emS[16 * EMP];
    __shared__ float rsS[2][16];
    size_t Gb = (size_t)b * 64;
    half8 A[4];
#pragma unroll
    for (int kc = 0; kc < 4; kc++)
        A[kc] = *(const half8*)&hSF[(((Gb + s) * 4 + kc) << 10) + l * 8];
    // MFMA phase with 2-deep register prefetch of the 4-frag quads (L3 latency cover)
    half8 bc[4], bn[4];
#pragma unroll
    for (int kc = 0; kc < 4; kc++)
        bc[kc] = *(const half8*)&hbrF[(((Gb + w * 16 + 0) * 4 + kc) << 10) + l * 8];
#pragma unroll
    for (int cg = 0; cg < 16; cg++) {
        if (cg < 15) {
#pragma unroll
            for (int kc = 0; kc < 4; kc++)
                bn[kc] = *(const half8*)&hbrF[(((Gb + w * 16 + cg + 1) * 4 + kc) << 10) + l * 8];
        }
        int c0 = w * 256 + cg * 16;
        floatx4 a = {0.f, 0.f, 0.f, 0.f};
#pragma unroll
        for (int kc = 0; kc < 4; kc++) a = MFMA(A[kc], bc[kc], a);
#pragma unroll
        for (int r = 0; r < 4; r++)
            emS[(q * 4 + r) * EMP + c0 + l15] = (half_t)a[r];
#pragma unroll
        for (int kc = 0; kc < 4; kc++) bc[kc] = bn[kc];
    }
    __syncthreads();
    const float CN = 0.000335462627903f;       // exp(-8)
    // batch-prefetch all 8 mask words (one exposed latency instead of 8)
    unsigned mvs[8];
#pragma unroll
    for (int tt = 0; tt < 8; tt++) {
        int task = tt * 4 + w;
        int rl = task >> 1, br = task & 1;
        size_t R = ((size_t)br << 14) + (size_t)b * 1024 + s * 16 + rl;
        mvs[tt] = (unsigned)mask16[R * 64 + l];
    }
#pragma unroll
    for (int tt = 0; tt < 8; tt++) {
        int task = tt * 4 + w;                 // 32 tasks: (rl, br)
        int rl = task >> 1, br = task & 1;
        size_t R = ((size_t)br << 14) + (size_t)b * 1024 + s * 16 + rl;
        unsigned mv = mvs[tt];
        half8 e0 = *(const half8*)&emS[rl * EMP + l * 16];
        half8 e1 = *(const half8*)&emS[rl * EMP + l * 16 + 8];
        half8 o0, o1;
        float rs = 0.f;
#pragma unroll
        for (int c2 = 0; c2 < 8; c2++) {
            float v0 = ((mv >> c2) & 1u) ? __expf((float)e0[c2] - 8.f) : 0.f;
            float v1 = ((mv >> (c2 + 8)) & 1u) ? __expf((float)e1[c2] - 8.f) : 0.f;
            o0[c2] = (half_t)v0; o1[c2] = (half_t)v1;
            rs += v0 + v1;
        }
        *(half8*)&Dm[R * 1024 + l * 16] = o0;
        *(half8*)&Dm[R * 1024 + l * 16 + 8] = o1;
        int cn = __popc(mv);
        rs += __shfl_xor(rs, 1); rs += __shfl_xor(rs, 2);
        rs += __shfl_xor(rs, 4); rs += __shfl_xor(rs, 8);
        rs += __shfl_xor(rs, 16); rs += __shfl_xor(rs, 32);
        cn += __shfl_xor(cn, 1); cn += __shfl_xor(cn, 2);
        cn += __shfl_xor(cn, 4); cn += __shfl_xor(cn, 8);
        cn += __shfl_xor(cn, 16); cn += __shfl_xor(cn, 32);
        if (l == 0) {
            float rv = 1.f / (rs + (1024.f - (float)cn) * CN);
            rsr[R] = rv;
            rsS[br][rl] = rv;
        }
    }
    __syncthreads();
    // hbrsT[(br,b)][d][i] = rsr[i] * hbrT[b][d][i]
    {
        int d = t >> 1, br = t & 1;
        const half_t* hp = hbrT + ((size_t)b * 128 + d) * 1024 + s * 16;
        half8 a0 = *(const half8*)hp, a1 = *(const half8*)(hp + 8);
        half8 r0, r1;
#pragma unroll
        for (int e = 0; e < 8; e++) {
            r0[e] = (half_t)((float)a0[e] * rsS[br][e]);
            r1[e] = (half_t)((float)a1[e] * rsS[br][8 + e]);
        }
        half_t* op = hbrsT + (((size_t)((br << 4) + b)) * 128 + d) * 1024 + s * 16;
        *(half8*)op = r0;
        *(half8*)(op + 8) = r1;
    }
}

// ---------------- dense az GEMM, staged (§5), BM=64, 2 blocks/CU,
// 2-TILE-DEEP register prefetch (named sets, hand-unrolled x2).
__global__ __launch_bounds__(512)
void k_azd(const half_t* __restrict__ Dm, const float* __restrict__ rsr,
           const half_t* __restrict__ BT, const half_t* __restrict__ hbr16,
           const float* __restrict__ gw, const float* __restrict__ gb_,
           float* __restrict__ cfb, half_t* __restrict__ outR, half_t* __restrict__ outT,
           int mode) {
    __shared__ union {
        struct { half_t A[2][64][72]; half_t B[2][128][72]; } s;
        half_t az[64][136];
    } sm;
    int t = threadIdx.x, w = t >> 6, l = t & 63, q = l >> 4, l15 = l & 15;
    int wi = w & 3, wd = w >> 2;               // i-group (16 rows) / d-half (64)
    int bid = blockIdx.x;
    int slice = bid & 31, tile = bid >> 5;     // 16 tiles of 64 rows
    int br = slice & 1, b = slice >> 1;
    int c = (br << 4) + b;
    int i0 = tile * 64;
    const half_t* Dp = Dm + ((size_t)c << 20) + (size_t)i0 * 1024;
    const half_t* Bp = BT + ((size_t)c << 17);
    int ar = t >> 3, ac = (t & 7) * 8;         // staging coords
    // two register prefetch sets (A=even tiles, B=odd tiles)
    half8 raA, rbA0, rbA1, raB, rbB0, rbB1;
    raA  = *(const half8*)&Dp[(size_t)ar * 1024 + ac];
    rbA0 = *(const half8*)&Bp[(size_t)ar * 1024 + ac];
    rbA1 = *(const half8*)&Bp[(size_t)(ar + 64) * 1024 + ac];
    raB  = *(const half8*)&Dp[(size_t)ar * 1024 + 64 + ac];
    rbB0 = *(const half8*)&Bp[(size_t)ar * 1024 + 64 + ac];
    rbB1 = *(const half8*)&Bp[(size_t)(ar + 64) * 1024 + 64 + ac];
    *(half8*)&sm.s.A[0][ar][ac] = raA;
    *(half8*)&sm.s.B[0][ar][ac] = rbA0;
    *(half8*)&sm.s.B[0][ar + 64][ac] = rbA1;
    __syncthreads();
    floatx4 acc[4] = {};
    for (int kt = 0; kt < 16; kt += 2) {
        // ---- even tile kt (LDS buf 0); issue T(kt+2) into set A
        if (kt < 14) {
            int ko = (kt + 2) * 64;
            raA  = *(const half8*)&Dp[(size_t)ar * 1024 + ko + ac];
            rbA0 = *(const half8*)&Bp[(size_t)ar * 1024 + ko + ac];
            rbA1 = *(const half8*)&Bp[(size_t)(ar + 64) * 1024 + ko + ac];
        }
#pragma unroll
        for (int kk = 0; kk < 2; kk++) {
            half8 af = *(const half8*)&sm.s.A[0][wi * 16 + l15][kk * 32 + q * 8];
#pragma unroll
            for (int nf = 0; nf < 4; nf++) {
                half8 bf = *(const half8*)&sm.s.B[0][wd * 64 + nf * 16 + l15][kk * 32 + q * 8];
                acc[nf] = MFMA(af, bf, acc[nf]);
            }
        }
        __syncthreads();
        // write T(kt+1) from set B -> LDS buf 1
        *(half8*)&sm.s.A[1][ar][ac] = raB;
        *(half8*)&sm.s.B[1][ar][ac] = rbB0;
        *(half8*)&sm.s.B[1][ar + 64][ac] = rbB1;
        __syncthreads();
        // ---- odd tile kt+1 (LDS buf 1); issue T(kt+3) into set B
        if (kt + 1 < 14) {
            int ko = (kt + 3) * 64;
            raB  = *(const half8*)&Dp[(size_t)ar * 1024 + ko + ac];
            rbB0 = *(const half8*)&Bp[(size_t)ar * 1024 + ko + ac];
            rbB1 = *(const half8*)&Bp[(size_t)(ar + 64) * 1024 + ko + ac];
        }
#pragma unroll
        for (int kk = 0; kk < 2; kk++) {
            half8 af = *(const half8*)&sm.s.A[1][wi * 16 + l15][kk * 32 + q * 8];
#pragma unroll
            for (int nf = 0; nf < 4; nf++) {
                half8 bf = *(const half8*)&sm.s.B[1][wd * 64 + nf * 16 + l15][kk * 32 + q * 8];
                acc[nf] = MFMA(af, bf, acc[nf]);
            }
        }
        __syncthreads();
        if (kt + 2 < 16) {
            // write T(kt+2) from set A -> LDS buf 0
            *(half8*)&sm.s.A[0][ar][ac] = raA;
            *(half8*)&sm.s.B[0][ar][ac] = rbA0;
            *(half8*)&sm.s.B[0][ar + 64][ac] = rbA1;
            __syncthreads();
        }
    }
    // acc -> az tile (all compute synced; az aliases stage buffers)
#pragma unroll
    for (int nf = 0; nf < 4; nf++)
#pragma unroll
        for (int r = 0; r < 4; r++)
            sm.az[wi * 16 + q * 4 + r][wd * 64 + nf * 16 + l15] = (half_t)acc[nf][r];
    __syncthreads();
#pragma unroll
    for (int it = 0; it < 2; it++) {
        int iloc = it * 32 + (t >> 4);         // 32 rows/pass, 16 lanes per row
        int i = i0 + iloc;
        int nb = b * 1024 + i;
        int R = c * 1024 + i;
        half8 az8 = *(const half8*)&sm.az[iloc][l15 * 8];
        half8 hv8 = *(const half8*)&hbr16[((size_t)nb << 7) + l15 * 8];
        float av[8], hv[8];
#pragma unroll
        for (int d = 0; d < 8; d++) {
            av[d] = fmaxf((float)az8[d], 0.f);
            hv[d] = (float)hv8[d];
        }
        float cf;
        if (mode >= 3) {
            const float* g1 = gw + l15 * 8;
            const float* g2 = gw + 128 + l15 * 8;
            float dp = 0.f;
#pragma unroll
            for (int d = 0; d < 8; d++) dp += hv[d] * g1[d] + av[d] * g2[d];
            dp += __shfl_xor(dp, 1); dp += __shfl_xor(dp, 2);
            dp += __shfl_xor(dp, 4); dp += __shfl_xor(dp, 8);
            cf = 1.f / (1.f + __expf(-(dp + gb_[0])));
            if (l15 == 0) cfb[R] = cf;
        } else {
            cf = cfb[R];
        }
        if (mode == 2 || mode == 4) {
            half8 o;
#pragma unroll
            for (int d = 0; d < 8; d++) o[d] = (half_t)(cf * hv[d] + (1.f - cf) * av[d]);
            *(half8*)&outR[(size_t)R * DD + l15 * 8] = o;
        } else {
            float sc = rsr[R];
#pragma unroll
            for (int d = 0; d < 8; d++)
                sm.az[iloc][l15 * 8 + d] = (half_t)(sc * (cf * hv[d] + (1.f - cf) * av[d]));
        }
    }
    if (mode == 1 || mode == 3) {
        __syncthreads();
        int d = t & 127, g4 = t >> 7;          // 4 i-chunks of 16
        half_t* op = outT + ((size_t)c * 128 + d) * 1024 + i0 + g4 * 16;
        half8 r0, r1;
#pragma unroll
        for (int e = 0; e < 8; e++) {
            r0[e] = sm.az[g4 * 16 + e][d];
            r1[e] = sm.az[g4 * 16 + 8 + e][d];
        }
        *(half8*)op = r0;
        *(half8*)(op + 8) = r1;
    }
}

// ---------------- partial masked pool of (z2 - z1), f16 inputs
__global__ __launch_bounds__(256)
void k_pool(const half_t* __restrict__ z2, const half_t* __restrict__ z1,
            const float* __restrict__ valid, float* __restrict__ part) {
    int b = blockIdx.y, s = blockIdx.x;
    int t = threadIdx.x, d = t & 127, hf = t >> 7;
    __shared__ float red[128];
    float acc = 0.f;
    int nbase = s * 128 + hf * 64;
    for (int n = nbase; n < nbase + 64; n++) {
        size_t gi = ((size_t)(b * 1024 + n) << 7) + d;
        acc += ((float)z2[gi] - (float)z1[gi]) * valid[b * 1024 + n];
    }
    if (hf) red[d] = acc;
    __syncthreads();
    if (!hf) part[(b * 8 + s) * 128 + d] = acc + red[d];
}

// ---------------- final reduce + MLP head
__global__ __launch_bounds__(128)
void k_mlp(const float* __restrict__ part, const float* __restrict__ valid,
           const float* __restrict__ w0, const float* __restrict__ b0,
           const float* __restrict__ w1, const float* __restrict__ b1,
           const float* __restrict__ w2, const float* __restrict__ b2,
           const float* __restrict__ w3, const float* __restrict__ b3,
           float* __restrict__ out) {
    int b = blockIdx.x, t = threadIdx.x;
    __shared__ float y0[DD], y1[DD];
    __shared__ float sred[2];
    float vs = 0.f;
    for (int n = t; n < NLEN; n += 128) vs += valid[b * NLEN + n];
    for (int off = 32; off; off >>= 1) vs += __shfl_down(vs, off);
    if ((t & 63) == 0) sred[t >> 6] = vs;
    __syncthreads();
    float vsum = sred[0] + sred[1];
    float acc = 0.f;
#pragma unroll
    for (int s = 0; s < 8; s++) acc += part[(b * 8 + s) * 128 + t];
    y0[t] = acc / vsum;
    __syncthreads();
    float a = b0[t];
    for (int k = 0; k < DD; k++) a += y0[k] * w0[t * DD + k];
    y1[t] = fmaxf(a, 0.f);
    __syncthreads();
    a = b1[t];
    for (int k = 0; k < DD; k++) a += y1[k] * w1[t * DD + k];
    y0[t] = fmaxf(a, 0.f);
    __syncthreads();
    a = b2[t];
    for (int k = 0; k < DD; k++) a += y0[k] * w2[t * DD + k];
    y1[t] = fmaxf(a, 0.f);
    __syncthreads();
    float pv = y1[t] * w3[t];
    for (int off = 32; off; off >>= 1) pv += __shfl_down(pv, off);
    if ((t & 63) == 0) sred[t >> 6] = pv;
    __syncthreads();
    if (t == 0) out[b] = 1.f / (1.f + __expf(-(sred[0] + sred[1] + b3[0])));
}

extern "C" void kernel_launch(void* const* d_in, const int* in_sizes, int n_in,
                              void* d_out, int out_size, void* d_ws, size_t ws_size,
                              hipStream_t stream) {
    (void)in_sizes; (void)n_in; (void)out_size; (void)ws_size;
    const float* x     = (const float*)d_in[0];
    const float* adj1  = (const float*)d_in[1];
    const float* adj2  = (const float*)d_in[2];
    const float* valid = (const float*)d_in[3];
    const float* Ew    = (const float*)d_in[4];
    const float* gW    = (const float*)d_in[5];
    const float* gb    = (const float*)d_in[6];
    const float* gA    = (const float*)d_in[7];
    const float* gatew = (const float*)d_in[8];
    const float* gateb = (const float*)d_in[9];
    const float* w0 = (const float*)d_in[10]; const float* b0 = (const float*)d_in[11];
    const float* w1 = (const float*)d_in[12]; const float* b1 = (const float*)d_in[13];
    const float* w2 = (const float*)d_in[14]; const float* b2 = (const float*)d_in[15];
    const float* w3 = (const float*)d_in[16]; const float* b3 = (const float*)d_in[17];
    float* out = (float*)d_out;

    char* p = (char*)d_ws;
    float* rsr  = (float*)p; p += 2 * BN * 4;
    float* cfb  = (float*)p; p += 2 * BN * 4;
    float* partb = (float*)p; p += (size_t)NB * 8 * 128 * 4;
    half_t* h16   = (half_t*)p; p += BND * 2;
    half_t* hbr16 = (half_t*)p; p += BND * 2;
    half_t* hbrF  = (half_t*)p; p += BND * 2;
    half_t* hSF   = (half_t*)p; p += BND * 2;
    half_t* hbrT  = (half_t*)p; p += BND * 2;       // [16 b][128 d][1024 i]
    half_t* hbrsT = (half_t*)p; p += 2 * BND * 2;   // [(br,b)][128 d][1024 i]
    half_t* zf    = (half_t*)p; p += 2 * BND * 2;   // layer outputs, row-major
    half_t* zTA   = (half_t*)p; p += 2 * BND * 2;   // hop buffers, transposed
    half_t* zTB   = (half_t*)p; p += 2 * BND * 2;
    unsigned short* mask16 = (unsigned short*)p; p += (size_t)2 * BN * 64 * 2;
    half_t* Dm   = (half_t*)p; p += (size_t)2 * BN * 1024 * 2;   // 64 MiB dense att
    half_t* Wf16 = (half_t*)p; p += (size_t)4 * 128 * 128 * 2;
    half_t* ST16 = (half_t*)p; p += (size_t)4 * 128 * 128 * 2;
    half_t* EwF  = (half_t*)p; p += (size_t)128 * 128 * 2;

    k_cast<<<320, 256, 0, stream>>>(gW, gA, Ew, Wf16, ST16, EwF);
    k_emb<<<512, 256, 0, stream>>>(x, EwF, h16);
    k_mask<<<8192, 256, 0, stream>>>(adj1, adj2, mask16);

    for (int k = 0; k < 4; k++) {
        int nhop = k + 1;
        const half_t* pa = k ? (zf + BND) : h16;
        const half_t* pb = k ? zf : nullptr;
        k_proj<<<512, 256, 0, stream>>>(pa, pb, Wf16 + (size_t)k * 16384, gb + k * 128,
                                        ST16 + (size_t)k * 16384, hbr16, hbrT, hbrF, hSF);
        k_E<<<dim3(64, NB), 256, 0, stream>>>(hSF, hbrF, mask16, hbrT, Dm, rsr, hbrsT);
        // hop 1 (gate computed in-kernel)
        if (nhop == 1) {
            k_azd<<<512, 512, 0, stream>>>(Dm, rsr, hbrsT, hbr16, gatew + k * 256, gateb + k,
                                           cfb, zf, (half_t*)nullptr, 4);
        } else {
            k_azd<<<512, 512, 0, stream>>>(Dm, rsr, hbrsT, hbr16, gatew + k * 256, gateb + k,
                                           cfb, (half_t*)nullptr, zTA, 3);
        }
        const half_t* srcT = zTA;
        for (int hop = 2; hop <= nhop; hop++) {
            if (hop == nhop) {
                k_azd<<<512, 512, 0, stream>>>(Dm, rsr, srcT, hbr16, gatew + k * 256, gateb + k,
                                               cfb, zf, (half_t*)nullptr, 2);
            } else {
                half_t* dT = (hop & 1) ? zTA : zTB;
                k_azd<<<512, 512, 0, stream>>>(Dm, rsr, srcT, hbr16, gatew + k * 256, gateb + k,
                                               cfb, (half_t*)nullptr, dT, 1);
                srcT = dT;
            }
        }
    }
    k_pool<<<dim3(8, NB), 256, 0, stream>>>(zf + BND, zf, valid, partb);
    k_mlp<<<16, 128, 0, stream>>>(partb, valid, w0, b0, w1, b1, w2, b2, w3, b3, out);
}

// Round 15
// 584.196 us; speedup vs baseline: 1.0867x; 1.0036x over previous
//
#include <hip/hip_runtime.h>

typedef _Float16 half_t;
typedef _Float16 half8 __attribute__((ext_vector_type(8)));
typedef float floatx4 __attribute__((ext_vector_type(4)));

#define MFMA(a,b,c) __builtin_amdgcn_mfma_f32_16x16x32_f16(a,b,c,0,0,0)

#define NB 16
#define NLEN 1024
#define DD 128
#define BN (NB*NLEN)                       // 16384 rows per branch
#define BND ((size_t)NB*NLEN*DD)
#define EMP 1044                           // emS row stride

// ---------------- weight casts: gW->Wf16, gA+gA^T->ST16, Ew->EwF
__global__ __launch_bounds__(256)
void k_cast(const float* __restrict__ gW, const float* __restrict__ gA,
            const float* __restrict__ Ew,
            half_t* __restrict__ Wf, half_t* __restrict__ STf, half_t* __restrict__ EwF) {
    int i = blockIdx.x * 256 + threadIdx.x;
    if (i < 65536) {
        Wf[i] = (half_t)gW[i];
        int base = i & ~16383;
        int lrem = i & 16383;
        int d = lrem >> 7, e = lrem & 127;
        STf[base + (e << 7) + d] = (half_t)(gA[i] + gA[base + (e << 7) + d]);
    } else {
        int j = i - 65536;
        EwF[j] = (half_t)Ew[j];
    }
}

// ---------------- embed as MFMA GEMM: h16 = f16(x) @ EwF^T
// XCD-aligned work id: rows for batch b are produced on XCD floor(b/2),
// matching k_proj's consumer mapping.
__global__ __launch_bounds__(256)
void k_emb(const float* __restrict__ x, const half_t* __restrict__ EwF,
           half_t* __restrict__ h16) {
    __shared__ half_t htile[32 * 136];
    __shared__ half_t otile[32 * 136];
    int bid = blockIdx.x;
    int g32 = (bid & 7) * 64 + (bid >> 3);
    int g = g32 * 32;
    int t = threadIdx.x;
    int w = t >> 6, l = t & 63, q = l >> 4, l15 = l & 15;
#pragma unroll
    for (int v = 0; v < 2; v++) {
        int idx = v * 256 + t; int r = idx >> 4, c8 = (idx & 15) * 8;
        const float* xp = &x[(size_t)(g + r) * DD + c8];
        float4 f0 = *(const float4*)xp;
        float4 f1 = *(const float4*)(xp + 4);
        half8 va;
        va[0] = (half_t)f0.x; va[1] = (half_t)f0.y; va[2] = (half_t)f0.z; va[3] = (half_t)f0.w;
        va[4] = (half_t)f1.x; va[5] = (half_t)f1.y; va[6] = (half_t)f1.z; va[7] = (half_t)f1.w;
        *(half8*)&htile[r * 136 + c8] = va;
    }
    __syncthreads();
    int rowh = (w & 1) * 16;
    int c0 = (w >> 1) * 4;
    half8 a1[4];
#pragma unroll
    for (int kc = 0; kc < 4; kc++) a1[kc] = *(const half8*)&htile[(rowh + l15) * 136 + kc * 32 + q * 8];
#pragma unroll
    for (int cc = 0; cc < 4; cc++) {
        int col = (c0 + cc) * 16 + l15;
        floatx4 a = {0.f, 0.f, 0.f, 0.f};
#pragma unroll
        for (int kc = 0; kc < 4; kc++) {
            half8 bf = *(const half8*)&EwF[((size_t)col << 7) + kc * 32 + q * 8];
            a = MFMA(a1[kc], bf, a);
        }
#pragma unroll
        for (int r = 0; r < 4; r++)
            otile[(rowh + q * 4 + r) * 136 + col] = (half_t)a[r];
    }
    __syncthreads();
#pragma unroll
    for (int v = 0; v < 2; v++) {
        int idx = v * 256 + t; int r = idx >> 4, c8 = (idx & 15) * 8;
        *(half8*)&h16[((size_t)(g + r) << 7) + c8] = *(const half8*)&otile[r * 136 + c8];
    }
}

// ---------------- adjacency bitmask build, coalesced via LDS bounce
__global__ __launch_bounds__(256)
void k_mask(const float* __restrict__ adj1, const float* __restrict__ adj2,
            unsigned short* __restrict__ mask16) {
    __shared__ float ls[4][1024];              // 16 KiB
    int tid = threadIdx.x;
    int bid = blockIdx.x;
    int w = tid >> 6, l = tid & 63;
    int R = bid * 4 + w;
    int br = R >> 14, nb = R & 16383;
    const float* arow = (br ? adj2 : adj1) + (size_t)nb * 1024;
#pragma unroll
    for (int c = 0; c < 4; c++)
        *(float4*)&ls[w][c * 256 + l * 4] = *(const float4*)&arow[c * 256 + l * 4];
    __syncthreads();
    unsigned m = 0u;
#pragma unroll
    for (int c = 0; c < 4; c++) {
        float4 v = *(const float4*)&ls[w][l * 16 + c * 4];
        m |= (v.x > 0.f ? 1u : 0u) << (c * 4);
        m |= (v.y > 0.f ? 1u : 0u) << (c * 4 + 1);
        m |= (v.z > 0.f ? 1u : 0u) << (c * 4 + 2);
        m |= (v.w > 0.f ? 1u : 0u) << (c * 4 + 3);
    }
    mask16[(size_t)R * 64 + l] = (unsigned short)m;
}

// ---------------- proj (MFMA): in = pa - pb (f16); hbr = in@W^T + b ; hS = hbr@S
// XCD-aligned: g32 = (bid&7)*64 + (bid>>3) -> batch b's panels produced on
// XCD floor(b/2) where k_E consumes them (L2-local instead of L3).
__global__ __launch_bounds__(256)
void k_proj(const half_t* __restrict__ pa, const half_t* __restrict__ pb,
            const half_t* __restrict__ Wf, const float* __restrict__ bias,
            const half_t* __restrict__ STf,
            half_t* __restrict__ hbr16, half_t* __restrict__ hbrT,
            half_t* __restrict__ hbrF, half_t* __restrict__ hSF) {
    __shared__ half_t htile[32 * 136];
    __shared__ half_t hbtile[32 * 136];
    int bid = blockIdx.x;
    int g32 = (bid & 7) * 64 + (bid >> 3);
    int g = g32 * 32;
    int t = threadIdx.x;
    int w = t >> 6, l = t & 63, q = l >> 4, l15 = l & 15;
#pragma unroll
    for (int v = 0; v < 2; v++) {
        int idx = v * 256 + t; int r = idx >> 4, c8 = (idx & 15) * 8;
        half8 va = *(const half8*)&pa[((size_t)(g + r) << 7) + c8];
        if (pb) {
            half8 vb = *(const half8*)&pb[((size_t)(g + r) << 7) + c8];
            va = va - vb;
        }
        *(half8*)&htile[r * 136 + c8] = va;
    }
    __syncthreads();
    int rowh = (w & 1) * 16;
    int c0 = (w >> 1) * 4;
    half8 a1[4];
#pragma unroll
    for (int kc = 0; kc < 4; kc++) a1[kc] = *(const half8*)&htile[(rowh + l15) * 136 + kc * 32 + q * 8];
    floatx4 acc[4];
#pragma unroll
    for (int cc = 0; cc < 4; cc++) {
        int col = (c0 + cc) * 16 + l15;
        floatx4 a = {0.f, 0.f, 0.f, 0.f};
#pragma unroll
        for (int kc = 0; kc < 4; kc++) {
            half8 bf = *(const half8*)&Wf[((size_t)col << 7) + kc * 32 + q * 8];
            a = MFMA(a1[kc], bf, a);
        }
        float bv = bias[col];
        a.x += bv; a.y += bv; a.z += bv; a.w += bv;
        acc[cc] = a;
    }
#pragma unroll
    for (int cc = 0; cc < 4; cc++) {
        int col = (c0 + cc) * 16 + l15;
#pragma unroll
        for (int r = 0; r < 4; r++)
            hbtile[(rowh + q * 4 + r) * 136 + col] = (half_t)acc[cc][r];
    }
    __syncthreads();
    half8 a2[4];
#pragma unroll
    for (int kc = 0; kc < 4; kc++) a2[kc] = *(const half8*)&hbtile[(rowh + l15) * 136 + kc * 32 + q * 8];
#pragma unroll
    for (int cc = 0; cc < 4; cc++) {
        int col = (c0 + cc) * 16 + l15;
        floatx4 a = {0.f, 0.f, 0.f, 0.f};
#pragma unroll
        for (int kc = 0; kc < 4; kc++) {
            half8 bf = *(const half8*)&STf[((size_t)col << 7) + kc * 32 + q * 8];
            a = MFMA(a2[kc], bf, a);
        }
        acc[cc] = a;
    }
    __syncthreads();
#pragma unroll
    for (int cc = 0; cc < 4; cc++) {
        int col = (c0 + cc) * 16 + l15;
#pragma unroll
        for (int r = 0; r < 4; r++) htile[(rowh + q * 4 + r) * 136 + col] = (half_t)acc[cc][r];
    }
    __syncthreads();
#pragma unroll
    for (int v = 0; v < 2; v++) {
        int idx = v * 256 + t; int r = idx >> 4, c8 = (idx & 15) * 8;
        *(half8*)&hbr16[((size_t)(g + r) << 7) + c8] = *(const half8*)&hbtile[r * 136 + c8];
    }
    // transposed hbr: hbrT[b][d][i]
    {
        int b_ = g >> 10, gi = g & 1023;
        int d = t >> 1, hh = t & 1;
        half8 r0, r1;
#pragma unroll
        for (int e = 0; e < 8; e++) {
            r0[e] = hbtile[(hh * 16 + e) * 136 + d];
            r1[e] = hbtile[(hh * 16 + 8 + e) * 136 + d];
        }
        half_t* op = hbrT + ((size_t)b_ * 128 + d) * 1024 + gi + hh * 16;
        *(half8*)op = r0;
        *(half8*)(op + 8) = r1;
    }
#pragma unroll
    for (int v = 0; v < 2; v++) {
        int fi = v * 256 + t;
        int g2 = fi >> 8, kc = (fi >> 6) & 3, li = fi & 63;
        int src = (g2 * 16 + (li & 15)) * 136 + kc * 32 + (li >> 4) * 8;
        size_t dst = (((size_t)(g32 * 2 + g2) * 4 + kc) << 10) + li * 8;
        *(half8*)&hbrF[dst] = *(const half8*)&hbtile[src];
        *(half8*)&hSF[dst]  = *(const half8*)&htile[src];
    }
}

// ---------------- E: em strip (MFMA, 1-deep prefetched hbrF loads) ->
// DENSE D rows (mask?exp:0, mask loads batch-prefetched), rsr, hbrsT.
__global__ __launch_bounds__(256)
void k_E(const half_t* __restrict__ hSF, const half_t* __restrict__ hbrF,
         const unsigned short* __restrict__ mask16, const half_t* __restrict__ hbrT,
         half_t* __restrict__ Dm, float* __restrict__ rsr, half_t* __restrict__ hbrsT) {
    int hw = blockIdx.y * 64 + blockIdx.x;
    int wk = (hw & 7) * 128 + (hw >> 3);
    int b = wk >> 6, s = wk & 63;              // 64 strips of 16 rows per batch
    int t = threadIdx.x, w = t >> 6, l = t & 63, q = l >> 4, l15 = l & 15;
    __shared__ half_t emS[16 * EMP];
    __shared__ float rsS[2][16];
    size_t Gb = (size_t)b * 64;
    half8 A[4];
#pragma unroll
    for (int kc = 0; kc < 4; kc++)
        A[kc] = *(const half8*)&hSF[(((Gb + s) * 4 + kc) << 10) + l * 8];
    // MFMA phase with 1-deep register prefetch of the 4-frag quads
    half8 bc[4], bn[4];
#pragma unroll
    for (int kc = 0; kc < 4; kc++)
        bc[kc] = *(const half8*)&hbrF[(((Gb + w * 16 + 0) * 4 + kc) << 10) + l * 8];
#pragma unroll
    for (int cg = 0; cg < 16; cg++) {
        if (cg < 15) {
#pragma unroll
            for (int kc = 0; kc < 4; kc++)
                bn[kc] = *(const half8*)&hbrF[(((Gb + w * 16 + cg + 1) * 4 + kc) << 10) + l * 8];
        }
        int c0 = w * 256 + cg * 16;
        floatx4 a = {0.f, 0.f, 0.f, 0.f};
#pragma unroll
        for (int kc = 0; kc < 4; kc++) a = MFMA(A[kc], bc[kc], a);
#pragma unroll
        for (int r = 0; r < 4; r++)
            emS[(q * 4 + r) * EMP + c0 + l15] = (half_t)a[r];
#pragma unroll
        for (int kc = 0; kc < 4; kc++) bc[kc] = bn[kc];
    }
    __syncthreads();
    const float CN = 0.000335462627903f;       // exp(-8)
    // batch-prefetch all 8 mask words
    unsigned mvs[8];
#pragma unroll
    for (int tt = 0; tt < 8; tt++) {
        int task = tt * 4 + w;
        int rl = task >> 1, br = task & 1;
        size_t R = ((size_t)br << 14) + (size_t)b * 1024 + s * 16 + rl;
        mvs[tt] = (unsigned)mask16[R * 64 + l];
    }
#pragma unroll
    for (int tt = 0; tt < 8; tt++) {
        int task = tt * 4 + w;                 // 32 tasks: (rl, br)
        int rl = task >> 1, br = task & 1;
        size_t R = ((size_t)br << 14) + (size_t)b * 1024 + s * 16 + rl;
        unsigned mv = mvs[tt];
        half8 e0 = *(const half8*)&emS[rl * EMP + l * 16];
        half8 e1 = *(const half8*)&emS[rl * EMP + l * 16 + 8];
        half8 o0, o1;
        float rs = 0.f;
#pragma unroll
        for (int c2 = 0; c2 < 8; c2++) {
            float v0 = ((mv >> c2) & 1u) ? __expf((float)e0[c2] - 8.f) : 0.f;
            float v1 = ((mv >> (c2 + 8)) & 1u) ? __expf((float)e1[c2] - 8.f) : 0.f;
            o0[c2] = (half_t)v0; o1[c2] = (half_t)v1;
            rs += v0 + v1;
        }
        *(half8*)&Dm[R * 1024 + l * 16] = o0;
        *(half8*)&Dm[R * 1024 + l * 16 + 8] = o1;
        int cn = __popc(mv);
        rs += __shfl_xor(rs, 1); rs += __shfl_xor(rs, 2);
        rs += __shfl_xor(rs, 4); rs += __shfl_xor(rs, 8);
        rs += __shfl_xor(rs, 16); rs += __shfl_xor(rs, 32);
        cn += __shfl_xor(cn, 1); cn += __shfl_xor(cn, 2);
        cn += __shfl_xor(cn, 4); cn += __shfl_xor(cn, 8);
        cn += __shfl_xor(cn, 16); cn += __shfl_xor(cn, 32);
        if (l == 0) {
            float rv = 1.f / (rs + (1024.f - (float)cn) * CN);
            rsr[R] = rv;
            rsS[br][rl] = rv;
        }
    }
    __syncthreads();
    // hbrsT[(br,b)][d][i] = rsr[i] * hbrT[b][d][i]
    {
        int d = t >> 1, br = t & 1;
        const half_t* hp = hbrT + ((size_t)b * 128 + d) * 1024 + s * 16;
        half8 a0 = *(const half8*)hp, a1 = *(const half8*)(hp + 8);
        half8 r0, r1;
#pragma unroll
        for (int e = 0; e < 8; e++) {
            r0[e] = (half_t)((float)a0[e] * rsS[br][e]);
            r1[e] = (half_t)((float)a1[e] * rsS[br][8 + e]);
        }
        half_t* op = hbrsT + (((size_t)((br << 4) + b)) * 128 + d) * 1024 + s * 16;
        *(half8*)op = r0;
        *(half8*)(op + 8) = r1;
    }
}

// ---------------- dense az GEMM, staged (§5), BM=64, 2 blocks/CU,
// 2-TILE-DEEP register prefetch. XCD-aligned slice mapping:
// slice = (bid&7)*4 + ((bid>>3)&3) -> slice 2b+br runs on XCD floor(b/2),
// matching k_E's hbrsT/Dm/rsr production (L2-local B panels).
__global__ __launch_bounds__(512)
void k_azd(const half_t* __restrict__ Dm, const float* __restrict__ rsr,
           const half_t* __restrict__ BT, const half_t* __restrict__ hbr16,
           const float* __restrict__ gw, const float* __restrict__ gb_,
           float* __restrict__ cfb, half_t* __restrict__ outR, half_t* __restrict__ outT,
           int mode) {
    __shared__ union {
        struct { half_t A[2][64][72]; half_t B[2][128][72]; } s;
        half_t az[64][136];
    } sm;
    int t = threadIdx.x, w = t >> 6, l = t & 63, q = l >> 4, l15 = l & 15;
    int wi = w & 3, wd = w >> 2;               // i-group (16 rows) / d-half (64)
    int bid = blockIdx.x;
    int slice = (bid & 7) * 4 + ((bid >> 3) & 3);
    int tile  = bid >> 5;                      // 16 tiles of 64 rows
    int br = slice & 1, b = slice >> 1;
    int c = (br << 4) + b;
    int i0 = tile * 64;
    const half_t* Dp = Dm + ((size_t)c << 20) + (size_t)i0 * 1024;
    const half_t* Bp = BT + ((size_t)c << 17);
    int ar = t >> 3, ac = (t & 7) * 8;         // staging coords
    // two register prefetch sets (A=even tiles, B=odd tiles)
    half8 raA, rbA0, rbA1, raB, rbB0, rbB1;
    raA  = *(const half8*)&Dp[(size_t)ar * 1024 + ac];
    rbA0 = *(const half8*)&Bp[(size_t)ar * 1024 + ac];
    rbA1 = *(const half8*)&Bp[(size_t)(ar + 64) * 1024 + ac];
    raB  = *(const half8*)&Dp[(size_t)ar * 1024 + 64 + ac];
    rbB0 = *(const half8*)&Bp[(size_t)ar * 1024 + 64 + ac];
    rbB1 = *(const half8*)&Bp[(size_t)(ar + 64) * 1024 + 64 + ac];
    *(half8*)&sm.s.A[0][ar][ac] = raA;
    *(half8*)&sm.s.B[0][ar][ac] = rbA0;
    *(half8*)&sm.s.B[0][ar + 64][ac] = rbA1;
    __syncthreads();
    floatx4 acc[4] = {};
    for (int kt = 0; kt < 16; kt += 2) {
        // ---- even tile kt (LDS buf 0); issue T(kt+2) into set A
        if (kt < 14) {
            int ko = (kt + 2) * 64;
            raA  = *(const half8*)&Dp[(size_t)ar * 1024 + ko + ac];
            rbA0 = *(const half8*)&Bp[(size_t)ar * 1024 + ko + ac];
            rbA1 = *(const half8*)&Bp[(size_t)(ar + 64) * 1024 + ko + ac];
        }
#pragma unroll
        for (int kk = 0; kk < 2; kk++) {
            half8 af = *(const half8*)&sm.s.A[0][wi * 16 + l15][kk * 32 + q * 8];
#pragma unroll
            for (int nf = 0; nf < 4; nf++) {
                half8 bf = *(const half8*)&sm.s.B[0][wd * 64 + nf * 16 + l15][kk * 32 + q * 8];
                acc[nf] = MFMA(af, bf, acc[nf]);
            }
        }
        __syncthreads();
        // write T(kt+1) from set B -> LDS buf 1
        *(half8*)&sm.s.A[1][ar][ac] = raB;
        *(half8*)&sm.s.B[1][ar][ac] = rbB0;
        *(half8*)&sm.s.B[1][ar + 64][ac] = rbB1;
        __syncthreads();
        // ---- odd tile kt+1 (LDS buf 1); issue T(kt+3) into set B
        if (kt + 1 < 14) {
            int ko = (kt + 3) * 64;
            raB  = *(const half8*)&Dp[(size_t)ar * 1024 + ko + ac];
            rbB0 = *(const half8*)&Bp[(size_t)ar * 1024 + ko + ac];
            rbB1 = *(const half8*)&Bp[(size_t)(ar + 64) * 1024 + ko + ac];
        }
#pragma unroll
        for (int kk = 0; kk < 2; kk++) {
            half8 af = *(const half8*)&sm.s.A[1][wi * 16 + l15][kk * 32 + q * 8];
#pragma unroll
            for (int nf = 0; nf < 4; nf++) {
                half8 bf = *(const half8*)&sm.s.B[1][wd * 64 + nf * 16 + l15][kk * 32 + q * 8];
                acc[nf] = MFMA(af, bf, acc[nf]);
            }
        }
        __syncthreads();
        if (kt + 2 < 16) {
            // write T(kt+2) from set A -> LDS buf 0
            *(half8*)&sm.s.A[0][ar][ac] = raA;
            *(half8*)&sm.s.B[0][ar][ac] = rbA0;
            *(half8*)&sm.s.B[0][ar + 64][ac] = rbA1;
            __syncthreads();
        }
    }
    // acc -> az tile (all compute synced; az aliases stage buffers)
#pragma unroll
    for (int nf = 0; nf < 4; nf++)
#pragma unroll
        for (int r = 0; r < 4; r++)
            sm.az[wi * 16 + q * 4 + r][wd * 64 + nf * 16 + l15] = (half_t)acc[nf][r];
    __syncthreads();
#pragma unroll
    for (int it = 0; it < 2; it++) {
        int iloc = it * 32 + (t >> 4);         // 32 rows/pass, 16 lanes per row
        int i = i0 + iloc;
        int nb = b * 1024 + i;
        int R = c * 1024 + i;
        half8 az8 = *(const half8*)&sm.az[iloc][l15 * 8];
        half8 hv8 = *(const half8*)&hbr16[((size_t)nb << 7) + l15 * 8];
        float av[8], hv[8];
#pragma unroll
        for (int d = 0; d < 8; d++) {
            av[d] = fmaxf((float)az8[d], 0.f);
            hv[d] = (float)hv8[d];
        }
        float cf;
        if (mode >= 3) {
            const float* g1 = gw + l15 * 8;
            const float* g2 = gw + 128 + l15 * 8;
            float dp = 0.f;
#pragma unroll
            for (int d = 0; d < 8; d++) dp += hv[d] * g1[d] + av[d] * g2[d];
            dp += __shfl_xor(dp, 1); dp += __shfl_xor(dp, 2);
            dp += __shfl_xor(dp, 4); dp += __shfl_xor(dp, 8);
            cf = 1.f / (1.f + __expf(-(dp + gb_[0])));
            if (l15 == 0) cfb[R] = cf;
        } else {
            cf = cfb[R];
        }
        if (mode == 2 || mode == 4) {
            half8 o;
#pragma unroll
            for (int d = 0; d < 8; d++) o[d] = (half_t)(cf * hv[d] + (1.f - cf) * av[d]);
            *(half8*)&outR[(size_t)R * DD + l15 * 8] = o;
        } else {
            float sc = rsr[R];
#pragma unroll
            for (int d = 0; d < 8; d++)
                sm.az[iloc][l15 * 8 + d] = (half_t)(sc * (cf * hv[d] + (1.f - cf) * av[d]));
        }
    }
    if (mode == 1 || mode == 3) {
        __syncthreads();
        int d = t & 127, g4 = t >> 7;          // 4 i-chunks of 16
        half_t* op = outT + ((size_t)c * 128 + d) * 1024 + i0 + g4 * 16;
        half8 r0, r1;
#pragma unroll
        for (int e = 0; e < 8; e++) {
            r0[e] = sm.az[g4 * 16 + e][d];
            r1[e] = sm.az[g4 * 16 + 8 + e][d];
        }
        *(half8*)op = r0;
        *(half8*)(op + 8) = r1;
    }
}

// ---------------- partial masked pool of (z2 - z1), f16 inputs
__global__ __launch_bounds__(256)
void k_pool(const half_t* __restrict__ z2, const half_t* __restrict__ z1,
            const float* __restrict__ valid, float* __restrict__ part) {
    int b = blockIdx.y, s = blockIdx.x;
    int t = threadIdx.x, d = t & 127, hf = t >> 7;
    __shared__ float red[128];
    float acc = 0.f;
    int nbase = s * 128 + hf * 64;
    for (int n = nbase; n < nbase + 64; n++) {
        size_t gi = ((size_t)(b * 1024 + n) << 7) + d;
        acc += ((float)z2[gi] - (float)z1[gi]) * valid[b * 1024 + n];
    }
    if (hf) red[d] = acc;
    __syncthreads();
    if (!hf) part[(b * 8 + s) * 128 + d] = acc + red[d];
}

// ---------------- final reduce + MLP head
__global__ __launch_bounds__(128)
void k_mlp(const float* __restrict__ part, const float* __restrict__ valid,
           const float* __restrict__ w0, const float* __restrict__ b0,
           const float* __restrict__ w1, const float* __restrict__ b1,
           const float* __restrict__ w2, const float* __restrict__ b2,
           const float* __restrict__ w3, const float* __restrict__ b3,
           float* __restrict__ out) {
    int b = blockIdx.x, t = threadIdx.x;
    __shared__ float y0[DD], y1[DD];
    __shared__ float sred[2];
    float vs = 0.f;
    for (int n = t; n < NLEN; n += 128) vs += valid[b * NLEN + n];
    for (int off = 32; off; off >>= 1) vs += __shfl_down(vs, off);
    if ((t & 63) == 0) sred[t >> 6] = vs;
    __syncthreads();
    float vsum = sred[0] + sred[1];
    float acc = 0.f;
#pragma unroll
    for (int s = 0; s < 8; s++) acc += part[(b * 8 + s) * 128 + t];
    y0[t] = acc / vsum;
    __syncthreads();
    float a = b0[t];
    for (int k = 0; k < DD; k++) a += y0[k] * w0[t * DD + k];
    y1[t] = fmaxf(a, 0.f);
    __syncthreads();
    a = b1[t];
    for (int k = 0; k < DD; k++) a += y1[k] * w1[t * DD + k];
    y0[t] = fmaxf(a, 0.f);
    __syncthreads();
    a = b2[t];
    for (int k = 0; k < DD; k++) a += y0[k] * w2[t * DD + k];
    y1[t] = fmaxf(a, 0.f);
    __syncthreads();
    float pv = y1[t] * w3[t];
    for (int off = 32; off; off >>= 1) pv += __shfl_down(pv, off);
    if ((t & 63) == 0) sred[t >> 6] = pv;
    __syncthreads();
    if (t == 0) out[b] = 1.f / (1.f + __expf(-(sred[0] + sred[1] + b3[0])));
}

extern "C" void kernel_launch(void* const* d_in, const int* in_sizes, int n_in,
                              void* d_out, int out_size, void* d_ws, size_t ws_size,
                              hipStream_t stream) {
    (void)in_sizes; (void)n_in; (void)out_size; (void)ws_size;
    const float* x     = (const float*)d_in[0];
    const float* adj1  = (const float*)d_in[1];
    const float* adj2  = (const float*)d_in[2];
    const float* valid = (const float*)d_in[3];
    const float* Ew    = (const float*)d_in[4];
    const float* gW    = (const float*)d_in[5];
    const float* gb    = (const float*)d_in[6];
    const float* gA    = (const float*)d_in[7];
    const float* gatew = (const float*)d_in[8];
    const float* gateb = (const float*)d_in[9];
    const float* w0 = (const float*)d_in[10]; const float* b0 = (const float*)d_in[11];
    const float* w1 = (const float*)d_in[12]; const float* b1 = (const float*)d_in[13];
    const float* w2 = (const float*)d_in[14]; const float* b2 = (const float*)d_in[15];
    const float* w3 = (const float*)d_in[16]; const float* b3 = (const float*)d_in[17];
    float* out = (float*)d_out;

    char* p = (char*)d_ws;
    float* rsr  = (float*)p; p += 2 * BN * 4;
    float* cfb  = (float*)p; p += 2 * BN * 4;
    float* partb = (float*)p; p += (size_t)NB * 8 * 128 * 4;
    half_t* h16   = (half_t*)p; p += BND * 2;
    half_t* hbr16 = (half_t*)p; p += BND * 2;
    half_t* hbrF  = (half_t*)p; p += BND * 2;
    half_t* hSF   = (half_t*)p; p += BND * 2;
    half_t* hbrT  = (half_t*)p; p += BND * 2;       // [16 b][128 d][1024 i]
    half_t* hbrsT = (half_t*)p; p += 2 * BND * 2;   // [(br,b)][128 d][1024 i]
    half_t* zf    = (half_t*)p; p += 2 * BND * 2;   // layer outputs, row-major
    half_t* zTA   = (half_t*)p; p += 2 * BND * 2;   // hop buffers, transposed
    half_t* zTB   = (half_t*)p; p += 2 * BND * 2;
    unsigned short* mask16 = (unsigned short*)p; p += (size_t)2 * BN * 64 * 2;
    half_t* Dm   = (half_t*)p; p += (size_t)2 * BN * 1024 * 2;   // 64 MiB dense att
    half_t* Wf16 = (half_t*)p; p += (size_t)4 * 128 * 128 * 2;
    half_t* ST16 = (half_t*)p; p += (size_t)4 * 128 * 128 * 2;
    half_t* EwF  = (half_t*)p; p += (size_t)128 * 128 * 2;

    k_cast<<<320, 256, 0, stream>>>(gW, gA, Ew, Wf16, ST16, EwF);
    k_emb<<<512, 256, 0, stream>>>(x, EwF, h16);
    k_mask<<<8192, 256, 0, stream>>>(adj1, adj2, mask16);

    for (int k = 0; k < 4; k++) {
        int nhop = k + 1;
        const half_t* pa = k ? (zf + BND) : h16;
        const half_t* pb = k ? zf : nullptr;
        k_proj<<<512, 256, 0, stream>>>(pa, pb, Wf16 + (size_t)k * 16384, gb + k * 128,
                                        ST16 + (size_t)k * 16384, hbr16, hbrT, hbrF, hSF);
        k_E<<<dim3(64, NB), 256, 0, stream>>>(hSF, hbrF, mask16, hbrT, Dm, rsr, hbrsT);
        // hop 1 (gate computed in-kernel)
        if (nhop == 1) {
            k_azd<<<512, 512, 0, stream>>>(Dm, rsr, hbrsT, hbr16, gatew + k * 256, gateb + k,
                                           cfb, zf, (half_t*)nullptr, 4);
        } else {
            k_azd<<<512, 512, 0, stream>>>(Dm, rsr, hbrsT, hbr16, gatew + k * 256, gateb + k,
                                           cfb, (half_t*)nullptr, zTA, 3);
        }
        const half_t* srcT = zTA;
        for (int hop = 2; hop <= nhop; hop++) {
            if (hop == nhop) {
                k_azd<<<512, 512, 0, stream>>>(Dm, rsr, srcT, hbr16, gatew + k * 256, gateb + k,
                                               cfb, zf, (half_t*)nullptr, 2);
            } else {
                half_t* dT = (hop & 1) ? zTA : zTB;
                k_azd<<<512, 512, 0, stream>>>(Dm, rsr, srcT, hbr16, gatew + k * 256, gateb + k,
                                               cfb, (half_t*)nullptr, dT, 1);
                srcT = dT;
            }
        }
    }
    k_pool<<<dim3(8, NB), 256, 0, stream>>>(zf + BND, zf, valid, partb);
    k_mlp<<<16, 128, 0, stream>>>(partb, valid, w0, b0, w1, b1, w2, b2, w3, b3, out);
}